// Round 7
// baseline (331.189 us; speedup 1.0000x reference)
//
#include <hip/hip_runtime.h>
#include <cstdint>
#include <cstddef>

// Problem constants
#define B_    4
#define L_    4096
#define D_    1024
#define H_    16
#define HD_   64
#define ND3_  3072          // 3*D
#define M1_   16384         // B*L
#define NCH_  64            // number of chunks
#define CSZ_  64            // chunk size
#define SCALE_ 0.125f       // 1/sqrt(HD)

typedef __attribute__((ext_vector_type(8))) __bf16 bf16x8;
typedef __attribute__((ext_vector_type(4))) float f32x4;
typedef __attribute__((ext_vector_type(4))) unsigned int uint4v;

__device__ __forceinline__ float u2f(unsigned int u) { return __builtin_bit_cast(float, u); }
__device__ __forceinline__ unsigned int f2u(float f) { return __builtin_bit_cast(unsigned int, f); }
__device__ __forceinline__ float bf2f(unsigned short s) { return u2f(((unsigned int)s) << 16); }
__device__ __forceinline__ unsigned short f2bf(float f) {
  unsigned int u = f2u(f);
  u = u + 0x7fffu + ((u >> 16) & 1u);   // RNE
  return (unsigned short)(u >> 16);
}

// async global->LDS, 16B per lane. LDS dest wave-uniform base (+lane*16 implicit).
__device__ __forceinline__ void glds16(const unsigned short* g, unsigned short* l) {
  __builtin_amdgcn_global_load_lds(
      (const __attribute__((address_space(1))) void*)(uintptr_t)g,
      (__attribute__((address_space(3))) void*)(uintptr_t)l, 16, 0, 0);
}

// ---------------- fp32 -> bf16 cast ----------------
__global__ __launch_bounds__(256) void cast_kernel(const float* __restrict__ in,
                                                   unsigned short* __restrict__ out, int n)
{
  int i = (blockIdx.x * 256 + threadIdx.x) * 4;
  if (i + 3 < n) {
    float4 f = *(const float4*)(in + i);
    out[i + 0] = f2bf(f.x);
    out[i + 1] = f2bf(f.y);
    out[i + 2] = f2bf(f.z);
    out[i + 3] = f2bf(f.w);
  }
}

// ------------- bf16 NT GEMM, A via LDS / B via registers-from-L2: C = A @ Bm^T + bias ----
// BMxBN tile, BK=32, waves WM x WN. LDS holds ONLY A (triple buffer). B fragments stream
// global->VGPR (weights, L2-resident; bn-major XCD chunking keeps each XCD's B window in
// its 4MB L2). B regs double-buffered via manual 2x unroll (named sets, rule #20).
// FIFO vmcnt bookkeeping: per iter issues loadB(t+1) [FN loads] THEN stageA(t+2) [AR glds]
// (order pinned by sched_barrier). Top-of-iter queue = [A(t)xAR, B(t)xFN, A(t+1)xAR];
// s_waitcnt vmcnt(AR) drains exactly {A(t), B(t)}, keeps A(t+1) flying. Never 0 mid-loop.
// NEEDS >=2 blocks/CU to hide the B-gather L2 latency (round-6 lesson: 1 block/CU -> 2.5x).
// EPI 0: scatter into q/k/v (B,H,L,HD) bf16 with k*SCALE.  EPI 1: fp32 C out.
template<int EPI, int BM, int BN, int WM, int WN, int THREADS>
__global__ __launch_bounds__(THREADS, 2)
void gemm_breg(const unsigned short* __restrict__ A, const unsigned short* __restrict__ Bm,
               const float* __restrict__ bias,
               unsigned short* __restrict__ qo, unsigned short* __restrict__ ko,
               unsigned short* __restrict__ vo,
               float* __restrict__ Co, int M, int N, int K)
{
  constexpr int TR = THREADS / 4;     // rows covered per glds round
  constexpr int AR = BM / TR;         // glds per K-tile (1 or 2)
  constexpr int FM = BM / WM / 16;    // m-frags per wave
  constexpr int FN = BN / WN / 16;    // n-frags per wave
  constexpr int ASZ = BM * 32;

  __shared__ __align__(16) unsigned short Ab[3 * ASZ];

  // XCD-chunked swizzle; bn-major decode so same-XCD blocks share the B panel (L2-fit).
  const int nwg = gridDim.x;
  const int wg = (blockIdx.x & 7) * (nwg >> 3) + (blockIdx.x >> 3);
  const int nbm = M / BM;
  const int bm = wg % nbm, bn = wg / nbm;
  const int m0 = bm * BM, n0 = bn * BN;
  const int tid = threadIdx.x;
  const int lane = tid & 63, wid = tid >> 6;
  const int wr = wid / WN, wc = wid % WN;
  const int fl = lane & 15, fh = lane >> 4;

  // A staging lane constants (chunk-XOR swizzle, both sides)
  const int rowbase = wid * 16 + (lane >> 2);
  const int ckst = (lane & 3) ^ ((rowbase & 3) ^ ((rowbase >> 2) & 3));
  const int ckrd = fh ^ ((fl & 3) ^ ((fl >> 2) & 3));

  const int nt = K >> 5;   // must be even (K=1024 -> 32)

  f32x4 acc[FM][FN] = {};

  // per-lane B row pointers (NT: B-frag = rows of Bm)
  const unsigned short* bp[FN];
#pragma unroll
  for (int n = 0; n < FN; ++n)
    bp[n] = Bm + (size_t)(n0 + wc * (BN / WN) + n * 16 + fl) * K + fh * 8;

  auto stageA = [&](int kt, int d) {
#pragma unroll
    for (int s = 0; s < AR; ++s)
      glds16(A + (size_t)(m0 + s * TR + rowbase) * K + kt * 32 + ckst * 8,
             Ab + d * ASZ + s * TR * 32 + wid * 512);
  };

  uint4v rB0[FN], rB1[FN];

  // prologue: queue = [A0 xAR, B0 xFN, A1 xAR]
  stageA(0, 0);
  __builtin_amdgcn_sched_barrier(0);
#pragma unroll
  for (int n = 0; n < FN; ++n) rB0[n] = *(const uint4v*)(bp[n]);
  __builtin_amdgcn_sched_barrier(0);
  stageA(1, 1);
  __builtin_amdgcn_sched_barrier(0);

  auto iter = [&](int t, uint4v (&rcur)[FN], uint4v (&rnxt)[FN]) {
    if (t < nt - 1) {
      if constexpr (AR == 2) { asm volatile("s_waitcnt vmcnt(2)" ::: "memory"); }
      else                   { asm volatile("s_waitcnt vmcnt(1)" ::: "memory"); }
    } else                   { asm volatile("s_waitcnt vmcnt(0)" ::: "memory"); }
    __builtin_amdgcn_s_barrier();
    __builtin_amdgcn_sched_barrier(0);

    const unsigned short* Abuf = Ab + (t % 3) * ASZ;

    // issue next-tile B loads (must precede stageA glds in the vmem FIFO)
    if (t + 1 < nt) {
#pragma unroll
      for (int n = 0; n < FN; ++n)
        rnxt[n] = *(const uint4v*)(bp[n] + (size_t)(t + 1) * 32);
    }
    // A frags first half
    bf16x8 afrag[FM / 2];
#pragma unroll
    for (int m = 0; m < FM / 2; ++m)
      afrag[m] = *(const bf16x8*)(Abuf + (wr * (BM / WM) + m * 16 + fl) * 32 + ckrd * 8);
    __builtin_amdgcn_sched_barrier(0);
    if (t + 2 < nt) stageA(t + 2, (t + 2) % 3);
    __builtin_amdgcn_sched_barrier(0);
    asm volatile("s_waitcnt lgkmcnt(0)" ::: "memory");
    __builtin_amdgcn_sched_barrier(0);
    __builtin_amdgcn_s_setprio(1);
#pragma unroll
    for (int m = 0; m < FM / 2; ++m)
#pragma unroll
      for (int n = 0; n < FN; ++n)
        acc[m][n] = __builtin_amdgcn_mfma_f32_16x16x32_bf16(
            afrag[m], __builtin_bit_cast(bf16x8, rcur[n]), acc[m][n], 0, 0, 0);
    __builtin_amdgcn_s_setprio(0);

    // A frags second half
    bf16x8 afrag2[FM / 2];
#pragma unroll
    for (int m = 0; m < FM / 2; ++m)
      afrag2[m] = *(const bf16x8*)(Abuf + (wr * (BM / WM) + (m + FM / 2) * 16 + fl) * 32 + ckrd * 8);
    asm volatile("s_waitcnt lgkmcnt(0)" ::: "memory");
    __builtin_amdgcn_sched_barrier(0);
    __builtin_amdgcn_s_setprio(1);
#pragma unroll
    for (int m = 0; m < FM / 2; ++m)
#pragma unroll
      for (int n = 0; n < FN; ++n)
        acc[m + FM / 2][n] = __builtin_amdgcn_mfma_f32_16x16x32_bf16(
            afrag2[m], __builtin_bit_cast(bf16x8, rcur[n]), acc[m + FM / 2][n], 0, 0, 0);
    __builtin_amdgcn_s_setprio(0);
  };

  for (int tt = 0; tt < nt; tt += 2) {   // nt even; named B-reg sets, no dynamic index
    iter(tt + 0, rB0, rB1);
    iter(tt + 1, rB1, rB0);
  }

  // epilogue: C row_local = (lane>>4)*4 + r, col_local = lane&15  [guide §3, m89]
  const int rb = fh << 2;
#pragma unroll
  for (int m = 0; m < FM; ++m) {
#pragma unroll
    for (int n = 0; n < FN; ++n) {
#pragma unroll
      for (int r = 0; r < 4; ++r) {
        int row = m0 + wr * (BM / WM) + m * 16 + rb + r;
        int col = n0 + wc * (BN / WN) + n * 16 + fl;
        float val = acc[m][n][r] + bias[col];
        if constexpr (EPI == 0) {
          int which = col >> 10;          // n / 1024
          int hh = (col >> 6) & 15;       // (n/64)%16
          int hd = col & 63;
          int bb = row >> 12;             // row / L
          int tt2 = row & 4095;
          size_t idx = (((size_t)(bb * H_ + hh)) * L_ + tt2) * HD_ + hd;
          if (which == 0)      qo[idx] = f2bf(val);
          else if (which == 1) ko[idx] = f2bf(val * SCALE_);
          else                 vo[idx] = f2bf(val);
        } else {
          Co[(size_t)row * N + col] = val;
        }
      }
    }
  }
}

// ---------------- retention phase 1 (MFMA): A_c[a][b] = sum_j g^{63-j} v_j[a] k_j[b] ----------------
__global__ __launch_bounds__(256) void ret_phase1(
    const unsigned short* __restrict__ kb, const unsigned short* __restrict__ vb,
    const float* __restrict__ gamma_raw, unsigned short* __restrict__ Sbuf)
{
  int bhc = blockIdx.x;
  int c = bhc & 63, bh = bhc >> 6, h = bh & 15;
  float g = 1.f / (1.f + expf(-gamma_raw[h]));
  float lg2g = log2f(g);

  __shared__ __align__(16) unsigned short Kt[64][72];   // Kt[b][j] = K[j][b]
  __shared__ __align__(16) unsigned short Vwt[64][72];  // Vwt[a][j] = g^{63-j} V[j][a]

  int tid = threadIdx.x;
  size_t base = ((size_t)bh * L_ + (size_t)c * CSZ_) * HD_;
#pragma unroll
  for (int qq = 0; qq < 16; ++qq) {
    int e = tid + qq * 256;
    int j = e >> 6, col = e & 63;
    float wj = exp2f(lg2g * (float)(63 - j));
    Kt[col][j] = kb[base + e];
    Vwt[col][j] = f2bf(bf2f(vb[base + e]) * wj);
  }
  __syncthreads();

  int lane = tid & 63, w = tid >> 6;
  int fl = lane & 15, fh = lane >> 4;

  bf16x8 av0 = *(const bf16x8*)(&Vwt[w * 16 + fl][fh * 8]);
  bf16x8 av1 = *(const bf16x8*)(&Vwt[w * 16 + fl][32 + fh * 8]);

  int rb = fh << 2;
  unsigned short* out = Sbuf + (size_t)bhc * 4096;
#pragma unroll
  for (int jf = 0; jf < 4; ++jf) {
    bf16x8 bk0 = *(const bf16x8*)(&Kt[jf * 16 + fl][fh * 8]);
    bf16x8 bk1 = *(const bf16x8*)(&Kt[jf * 16 + fl][32 + fh * 8]);
    f32x4 z = {};
    z = __builtin_amdgcn_mfma_f32_16x16x32_bf16(av0, bk0, z, 0, 0, 0);
    z = __builtin_amdgcn_mfma_f32_16x16x32_bf16(av1, bk1, z, 0, 0, 0);
#pragma unroll
    for (int r = 0; r < 4; ++r) {
      int a = w * 16 + rb + r, bcol = jf * 16 + fl;
      out[a * 64 + bcol] = f2bf(z[r]);
    }
  }
}

// ---------------- retention phase 2: in-place decay scan over chunks (bf16 storage) ----------------
__global__ __launch_bounds__(256) void ret_phase2(unsigned short* __restrict__ Sbuf,
                                                  const float* __restrict__ gamma_raw)
{
  int bh = blockIdx.x >> 3, grp = blockIdx.x & 7;
  int h = bh & 15;
  float g = 1.f / (1.f + expf(-gamma_raw[h]));
  float gC = powf(g, 64.f);
  int e = (grp * 256 + threadIdx.x) * 2;
  unsigned short* base = Sbuf + (size_t)bh * (NCH_ * 4096) + e;
  float s0 = 0.f, s1 = 0.f;
  for (int c = 0; c < NCH_; ++c) {
    unsigned int u = *(unsigned int*)(base + (size_t)c * 4096);
    float a0 = bf2f((unsigned short)(u & 0xffffu));
    float a1 = bf2f((unsigned short)(u >> 16));
    *(unsigned int*)(base + (size_t)c * 4096) =
        (unsigned int)f2bf(s0) | ((unsigned int)f2bf(s1) << 16);
    s0 = gC * s0 + a0;
    s1 = gC * s1 + a1;
  }
}

// ---------------- retention phase 3 (MFMA): Y = (D ∘ QK^T) V + g^{i+1} (Q S^T) ----------------
__global__ __launch_bounds__(256) void ret_phase3(
    const unsigned short* __restrict__ qb, const unsigned short* __restrict__ kb,
    const unsigned short* __restrict__ vb, const unsigned short* __restrict__ Sbuf,
    const float* __restrict__ gamma_raw, unsigned short* __restrict__ y)
{
  int bhc = blockIdx.x;
  int c = bhc & 63, bh = bhc >> 6, h = bh & 15, b = bh >> 4;
  float g = 1.f / (1.f + expf(-gamma_raw[h]));
  float lg2g = log2f(g);

  __shared__ __align__(16) unsigned short Qs[64][72];
  __shared__ __align__(16) unsigned short Ks[64][72];
  __shared__ __align__(16) unsigned short Vt[64][72];  // Vt[a][j] = V[j][a]
  __shared__ __align__(16) unsigned short Sb[64][72];  // S rows (bf16)
  __shared__ __align__(16) unsigned short Ps[64][72];  // masked P (bf16)

  int tid = threadIdx.x;
  size_t base = ((size_t)bh * L_ + (size_t)c * CSZ_) * HD_;
  const unsigned short* Sp = Sbuf + (size_t)bhc * 4096;
#pragma unroll
  for (int qq = 0; qq < 16; ++qq) {
    int e = tid + qq * 256;
    int r = e >> 6, col = e & 63;
    Qs[r][col] = qb[base + e];
    Ks[r][col] = kb[base + e];
    Vt[col][r] = vb[base + e];
    Sb[r][col] = Sp[e];
  }
  __syncthreads();

  int lane = tid & 63, w = tid >> 6;
  int fl = lane & 15, fh = lane >> 4;
  int rb = fh << 2;

  bf16x8 aq0 = *(const bf16x8*)(&Qs[w * 16 + fl][fh * 8]);
  bf16x8 aq1 = *(const bf16x8*)(&Qs[w * 16 + fl][32 + fh * 8]);

  f32x4 pc[4], acc[4];
#pragma unroll
  for (int jf = 0; jf < 4; ++jf) {
    bf16x8 bk0 = *(const bf16x8*)(&Ks[jf * 16 + fl][fh * 8]);
    bf16x8 bk1 = *(const bf16x8*)(&Ks[jf * 16 + fl][32 + fh * 8]);
    f32x4 z = {};
    z = __builtin_amdgcn_mfma_f32_16x16x32_bf16(aq0, bk0, z, 0, 0, 0);
    z = __builtin_amdgcn_mfma_f32_16x16x32_bf16(aq1, bk1, z, 0, 0, 0);
    pc[jf] = z;

    bf16x8 bs0 = *(const bf16x8*)(&Sb[jf * 16 + fl][fh * 8]);
    bf16x8 bs1 = *(const bf16x8*)(&Sb[jf * 16 + fl][32 + fh * 8]);
    f32x4 zz = {};
    zz = __builtin_amdgcn_mfma_f32_16x16x32_bf16(aq0, bs0, zz, 0, 0, 0);
    zz = __builtin_amdgcn_mfma_f32_16x16x32_bf16(aq1, bs1, zz, 0, 0, 0);
    acc[jf] = zz;
  }

#pragma unroll
  for (int jf = 0; jf < 4; ++jf) {
#pragma unroll
    for (int r = 0; r < 4; ++r) {
      int i = w * 16 + rb + r, j = jf * 16 + fl;
      float val = (j <= i) ? pc[jf][r] * exp2f(lg2g * (float)(i - j)) : 0.f;
      Ps[i][j] = f2bf(val);
    }
  }

  float gi1[4];
#pragma unroll
  for (int r = 0; r < 4; ++r) gi1[r] = exp2f(lg2g * (float)(w * 16 + rb + r + 1));
#pragma unroll
  for (int jf = 0; jf < 4; ++jf)
#pragma unroll
    for (int r = 0; r < 4; ++r) acc[jf][r] *= gi1[r];

  __syncthreads();

  bf16x8 ap0 = *(const bf16x8*)(&Ps[w * 16 + fl][fh * 8]);
  bf16x8 ap1 = *(const bf16x8*)(&Ps[w * 16 + fl][32 + fh * 8]);
#pragma unroll
  for (int jf = 0; jf < 4; ++jf) {
    bf16x8 bv0 = *(const bf16x8*)(&Vt[jf * 16 + fl][fh * 8]);
    bf16x8 bv1 = *(const bf16x8*)(&Vt[jf * 16 + fl][32 + fh * 8]);
    acc[jf] = __builtin_amdgcn_mfma_f32_16x16x32_bf16(ap0, bv0, acc[jf], 0, 0, 0);
    acc[jf] = __builtin_amdgcn_mfma_f32_16x16x32_bf16(ap1, bv1, acc[jf], 0, 0, 0);
  }

  size_t yrow = ((size_t)(b * L_ + c * CSZ_)) * D_ + h * HD_;
#pragma unroll
  for (int jf = 0; jf < 4; ++jf) {
#pragma unroll
    for (int r = 0; r < 4; ++r) {
      int i = w * 16 + rb + r;
      y[yrow + (size_t)i * D_ + jf * 16 + fl] = f2bf(acc[jf][r]);
    }
  }
}

// ---------------- launch ----------------
extern "C" void kernel_launch(void* const* d_in, const int* in_sizes, int n_in,
                              void* d_out, int out_size, void* d_ws, size_t ws_size,
                              hipStream_t stream)
{
  const float* x        = (const float*)d_in[0];
  const float* Wqkv_w   = (const float*)d_in[1];
  const float* Wqkv_b   = (const float*)d_in[2];
  const float* out_w    = (const float*)d_in[3];
  const float* out_b    = (const float*)d_in[4];
  const float* gamma_raw= (const float*)d_in[5];
  float* out = (float*)d_out;

  // workspace carve-up (~210 MB)
  char* ws = (char*)d_ws;
  unsigned short* x_bf    = (unsigned short*)ws; ws += (size_t)16777216 * 2;
  unsigned short* wqkv_bf = (unsigned short*)ws; ws += (size_t)3145728 * 2;
  unsigned short* wout_bf = (unsigned short*)ws; ws += (size_t)1048576 * 2;
  unsigned short* qb      = (unsigned short*)ws; ws += (size_t)16777216 * 2;
  unsigned short* kb      = (unsigned short*)ws; ws += (size_t)16777216 * 2;
  unsigned short* vb      = (unsigned short*)ws; ws += (size_t)16777216 * 2;
  unsigned short* Sbuf    = (unsigned short*)ws; ws += (size_t)16777216 * 2;
  unsigned short* yb      = (unsigned short*)ws; ws += (size_t)16777216 * 2;

  cast_kernel<<<16384, 256, 0, stream>>>(x, x_bf, 16777216);
  cast_kernel<<<3072, 256, 0, stream>>>(Wqkv_w, wqkv_bf, 3145728);
  cast_kernel<<<1024, 256, 0, stream>>>(out_w, wout_bf, 1048576);

  // qkv = x @ Wqkv^T + b  -> q/k/v (B,H,L,HD), k pre-scaled.  grid 768 (3 blocks/CU)
  gemm_breg<0, 256, 256, 2, 4, 512><<<64 * 12, 512, 0, stream>>>(
      x_bf, wqkv_bf, Wqkv_b, qb, kb, vb, nullptr, M1_, ND3_, D_);

  ret_phase1<<<4096, 256, 0, stream>>>(kb, vb, gamma_raw, Sbuf);
  ret_phase2<<<512, 256, 0, stream>>>(Sbuf, gamma_raw);
  ret_phase3<<<4096, 256, 0, stream>>>(qb, kb, vb, Sbuf, gamma_raw, yb);

  // out = y @ out_w^T + out_b  (fp32 out).  128x256 tile, grid 512 (2 blocks/CU)
  gemm_breg<1, 128, 256, 2, 4, 512><<<128 * 4, 512, 0, stream>>>(
      yb, wout_bf, out_b, nullptr, nullptr, nullptr, out, M1_, D_, D_);
}

// Round 8
// 255.952 us; speedup vs baseline: 1.2939x; 1.2939x over previous
//
#include <hip/hip_runtime.h>
#include <cstdint>
#include <cstddef>

// Problem constants
#define B_    4
#define L_    4096
#define D_    1024
#define H_    16
#define HD_   64
#define ND3_  3072          // 3*D
#define M1_   16384         // B*L
#define NCH_  64            // number of chunks
#define CSZ_  64            // chunk size
#define SCALE_ 0.125f       // 1/sqrt(HD)

typedef __attribute__((ext_vector_type(8))) __bf16 bf16x8;
typedef __attribute__((ext_vector_type(4))) float f32x4;
typedef __attribute__((ext_vector_type(4))) unsigned int uint4v;

__device__ __forceinline__ float u2f(unsigned int u) { return __builtin_bit_cast(float, u); }
__device__ __forceinline__ unsigned int f2u(float f) { return __builtin_bit_cast(unsigned int, f); }
__device__ __forceinline__ float bf2f(unsigned short s) { return u2f(((unsigned int)s) << 16); }
__device__ __forceinline__ unsigned short f2bf(float f) {
  unsigned int u = f2u(f);
  u = u + 0x7fffu + ((u >> 16) & 1u);   // RNE
  return (unsigned short)(u >> 16);
}

// async global->LDS, 16B per lane. LDS dest wave-uniform base (+lane*16 implicit).
__device__ __forceinline__ void glds16(const unsigned short* g, unsigned short* l) {
  __builtin_amdgcn_global_load_lds(
      (const __attribute__((address_space(1))) void*)(uintptr_t)g,
      (__attribute__((address_space(3))) void*)(uintptr_t)l, 16, 0, 0);
}

// ---------------- fp32 -> bf16 cast ----------------
__global__ __launch_bounds__(256) void cast_kernel(const float* __restrict__ in,
                                                   unsigned short* __restrict__ out, int n)
{
  int i = (blockIdx.x * 256 + threadIdx.x) * 4;
  if (i + 3 < n) {
    float4 f = *(const float4*)(in + i);
    out[i + 0] = f2bf(f.x);
    out[i + 1] = f2bf(f.y);
    out[i + 2] = f2bf(f.z);
    out[i + 3] = f2bf(f.w);
  }
}

// ---------------- bf16 NT GEMM, pipelined, parametric tile: C = A @ Bm^T + bias --------
// Round-5 structure (best verified: QKV 117us): BMxBN tile, BK=32, triple-buffered LDS,
// one s_barrier + counted vmcnt(4) per K-tile (4 glds/thread/tile in program order; FIFO:
// newest 4 = tile t+1's stay in flight). Chunk-XOR swizzle both-sides. XCD-chunked blocks.
// Round-8 change: NO in-loop lgkmcnt(0)/sched_barrier/setprio pins — the compiler's own
// fine-grained lgkmcnt interleave (m97 precedent) schedules ds_read vs MFMA; source-level
// order-pinning is the measured anti-pattern (m141). Staging fences kept at tile top only.
// EPI 0: scatter into q/k/v (B,H,L,HD) bf16 with k*SCALE.  EPI 1: fp32 C out.
template<int EPI, int BM, int BN, int WM, int WN, int THREADS>
__global__ __launch_bounds__(THREADS, (THREADS == 512 ? 2 : 3))
void gemm_pipe(const unsigned short* __restrict__ A, const unsigned short* __restrict__ Bm,
               const float* __restrict__ bias,
               unsigned short* __restrict__ qo, unsigned short* __restrict__ ko,
               unsigned short* __restrict__ vo,
               float* __restrict__ Co, int M, int N, int K)
{
  constexpr int TR = THREADS / 4;     // rows covered per stage round
  constexpr int AR = BM / TR;         // glds rounds for A per tile
  constexpr int BRR = BN / TR;        // glds rounds for B per tile
  constexpr int FM = BM / WM / 16;    // m-frags per wave
  constexpr int FN = BN / WN / 16;    // n-frags per wave
  constexpr int ASZ = BM * 32, BSZ = BN * 32;

  __shared__ __align__(16) unsigned short Ab[3 * ASZ];
  __shared__ __align__(16) unsigned short Bb[3 * BSZ];

  const int nwg = gridDim.x;
  const int wg = (blockIdx.x & 7) * (nwg >> 3) + (blockIdx.x >> 3);
  const int nbn = N / BN;
  const int bm = wg / nbn, bn = wg - bm * nbn;
  const int m0 = bm * BM, n0 = bn * BN;
  const int tid = threadIdx.x;
  const int lane = tid & 63, wid = tid >> 6;
  const int wr = wid / WN, wc = wid % WN;
  const int fl = lane & 15, fh = lane >> 4;

  // staging lane constants (chunk-XOR swizzle, both sides)
  const int rowbase = wid * 16 + (lane >> 2);
  const int ckst = (lane & 3) ^ ((rowbase & 3) ^ ((rowbase >> 2) & 3));
  const int ckrd = fh ^ ((fl & 3) ^ ((fl >> 2) & 3));

  const int nt = K >> 5;

  f32x4 acc[FM][FN] = {};

  auto stageA = [&](int kt, int d) {
#pragma unroll
    for (int s = 0; s < AR; ++s)
      glds16(A + (size_t)(m0 + s * TR + rowbase) * K + kt * 32 + ckst * 8,
             Ab + d * ASZ + s * TR * 32 + wid * 512);
  };
  auto stageB = [&](int kt, int d) {
#pragma unroll
    for (int s = 0; s < BRR; ++s)
      glds16(Bm + (size_t)(n0 + s * TR + rowbase) * K + kt * 32 + ckst * 8,
             Bb + d * BSZ + s * TR * 32 + wid * 512);
  };

  // prologue: tiles 0,1 -> buffers 0,1 (8 glds/thread in flight)
  stageA(0, 0); stageB(0, 0);
  stageA(1, 1); stageB(1, 1);

  for (int t = 0; t < nt; ++t) {
    const int d = t % 3;
    if (t < nt - 1) { asm volatile("s_waitcnt vmcnt(4)" ::: "memory"); }
    else            { asm volatile("s_waitcnt vmcnt(0)" ::: "memory"); }
    __builtin_amdgcn_s_barrier();
    __builtin_amdgcn_sched_barrier(0);   // pin the fence; loop body free below

    const unsigned short* Abuf = Ab + d * ASZ;
    const unsigned short* Bbuf = Bb + d * BSZ;

    // phase 0: B frags + A frags (first half), stage A of t+2, MFMA
    bf16x8 bfrag[FN], afrag[FM / 2];
#pragma unroll
    for (int n = 0; n < FN; ++n)
      bfrag[n] = *(const bf16x8*)(Bbuf + (wc * (BN / WN) + n * 16 + fl) * 32 + ckrd * 8);
#pragma unroll
    for (int m = 0; m < FM / 2; ++m)
      afrag[m] = *(const bf16x8*)(Abuf + (wr * (BM / WM) + m * 16 + fl) * 32 + ckrd * 8);
    if (t + 2 < nt) stageA(t + 2, (t + 2) % 3);
#pragma unroll
    for (int m = 0; m < FM / 2; ++m)
#pragma unroll
      for (int n = 0; n < FN; ++n)
        acc[m][n] = __builtin_amdgcn_mfma_f32_16x16x32_bf16(afrag[m], bfrag[n], acc[m][n], 0, 0, 0);

    // phase 1: A frags (second half), stage B of t+2, MFMA
    bf16x8 afrag2[FM / 2];
#pragma unroll
    for (int m = 0; m < FM / 2; ++m)
      afrag2[m] = *(const bf16x8*)(Abuf + (wr * (BM / WM) + (m + FM / 2) * 16 + fl) * 32 + ckrd * 8);
    if (t + 2 < nt) stageB(t + 2, (t + 2) % 3);
#pragma unroll
    for (int m = 0; m < FM / 2; ++m)
#pragma unroll
      for (int n = 0; n < FN; ++n)
        acc[m + FM / 2][n] = __builtin_amdgcn_mfma_f32_16x16x32_bf16(afrag2[m], bfrag[n], acc[m + FM / 2][n], 0, 0, 0);

    __builtin_amdgcn_sched_barrier(0);   // keep next iter's fence from melting upward
  }

  // epilogue: C row_local = (lane>>4)*4 + r, col_local = lane&15  [guide §3, m89]
  const int rb = fh << 2;
#pragma unroll
  for (int m = 0; m < FM; ++m) {
#pragma unroll
    for (int n = 0; n < FN; ++n) {
#pragma unroll
      for (int r = 0; r < 4; ++r) {
        int row = m0 + wr * (BM / WM) + m * 16 + rb + r;
        int col = n0 + wc * (BN / WN) + n * 16 + fl;
        float val = acc[m][n][r] + bias[col];
        if constexpr (EPI == 0) {
          int which = col >> 10;          // n / 1024
          int hh = (col >> 6) & 15;       // (n/64)%16
          int hd = col & 63;
          int bb = row >> 12;             // row / L
          int tt2 = row & 4095;
          size_t idx = (((size_t)(bb * H_ + hh)) * L_ + tt2) * HD_ + hd;
          if (which == 0)      qo[idx] = f2bf(val);
          else if (which == 1) ko[idx] = f2bf(val * SCALE_);
          else                 vo[idx] = f2bf(val);
        } else {
          Co[(size_t)row * N + col] = val;
        }
      }
    }
  }
}

// ---------------- retention phase 1 (MFMA): A_c[a][b] = sum_j g^{63-j} v_j[a] k_j[b] ----------------
__global__ __launch_bounds__(256) void ret_phase1(
    const unsigned short* __restrict__ kb, const unsigned short* __restrict__ vb,
    const float* __restrict__ gamma_raw, unsigned short* __restrict__ Sbuf)
{
  int bhc = blockIdx.x;
  int c = bhc & 63, bh = bhc >> 6, h = bh & 15;
  float g = 1.f / (1.f + expf(-gamma_raw[h]));
  float lg2g = log2f(g);

  __shared__ __align__(16) unsigned short Kt[64][72];   // Kt[b][j] = K[j][b]
  __shared__ __align__(16) unsigned short Vwt[64][72];  // Vwt[a][j] = g^{63-j} V[j][a]

  int tid = threadIdx.x;
  size_t base = ((size_t)bh * L_ + (size_t)c * CSZ_) * HD_;
#pragma unroll
  for (int qq = 0; qq < 16; ++qq) {
    int e = tid + qq * 256;
    int j = e >> 6, col = e & 63;
    float wj = exp2f(lg2g * (float)(63 - j));
    Kt[col][j] = kb[base + e];
    Vwt[col][j] = f2bf(bf2f(vb[base + e]) * wj);
  }
  __syncthreads();

  int lane = tid & 63, w = tid >> 6;
  int fl = lane & 15, fh = lane >> 4;

  bf16x8 av0 = *(const bf16x8*)(&Vwt[w * 16 + fl][fh * 8]);
  bf16x8 av1 = *(const bf16x8*)(&Vwt[w * 16 + fl][32 + fh * 8]);

  int rb = fh << 2;
  unsigned short* out = Sbuf + (size_t)bhc * 4096;
#pragma unroll
  for (int jf = 0; jf < 4; ++jf) {
    bf16x8 bk0 = *(const bf16x8*)(&Kt[jf * 16 + fl][fh * 8]);
    bf16x8 bk1 = *(const bf16x8*)(&Kt[jf * 16 + fl][32 + fh * 8]);
    f32x4 z = {};
    z = __builtin_amdgcn_mfma_f32_16x16x32_bf16(av0, bk0, z, 0, 0, 0);
    z = __builtin_amdgcn_mfma_f32_16x16x32_bf16(av1, bk1, z, 0, 0, 0);
#pragma unroll
    for (int r = 0; r < 4; ++r) {
      int a = w * 16 + rb + r, bcol = jf * 16 + fl;
      out[a * 64 + bcol] = f2bf(z[r]);
    }
  }
}

// ---------------- retention phase 2: in-place decay scan over chunks (bf16 storage) ----------------
__global__ __launch_bounds__(256) void ret_phase2(unsigned short* __restrict__ Sbuf,
                                                  const float* __restrict__ gamma_raw)
{
  int bh = blockIdx.x >> 3, grp = blockIdx.x & 7;
  int h = bh & 15;
  float g = 1.f / (1.f + expf(-gamma_raw[h]));
  float gC = powf(g, 64.f);
  int e = (grp * 256 + threadIdx.x) * 2;
  unsigned short* base = Sbuf + (size_t)bh * (NCH_ * 4096) + e;
  float s0 = 0.f, s1 = 0.f;
  for (int c = 0; c < NCH_; ++c) {
    unsigned int u = *(unsigned int*)(base + (size_t)c * 4096);
    float a0 = bf2f((unsigned short)(u & 0xffffu));
    float a1 = bf2f((unsigned short)(u >> 16));
    *(unsigned int*)(base + (size_t)c * 4096) =
        (unsigned int)f2bf(s0) | ((unsigned int)f2bf(s1) << 16);
    s0 = gC * s0 + a0;
    s1 = gC * s1 + a1;
  }
}

// ---------------- retention phase 3 (MFMA): Y = (D ∘ QK^T) V + g^{i+1} (Q S^T) ----------------
__global__ __launch_bounds__(256) void ret_phase3(
    const unsigned short* __restrict__ qb, const unsigned short* __restrict__ kb,
    const unsigned short* __restrict__ vb, const unsigned short* __restrict__ Sbuf,
    const float* __restrict__ gamma_raw, unsigned short* __restrict__ y)
{
  int bhc = blockIdx.x;
  int c = bhc & 63, bh = bhc >> 6, h = bh & 15, b = bh >> 4;
  float g = 1.f / (1.f + expf(-gamma_raw[h]));
  float lg2g = log2f(g);

  __shared__ __align__(16) unsigned short Qs[64][72];
  __shared__ __align__(16) unsigned short Ks[64][72];
  __shared__ __align__(16) unsigned short Vt[64][72];  // Vt[a][j] = V[j][a]
  __shared__ __align__(16) unsigned short Sb[64][72];  // S rows (bf16)
  __shared__ __align__(16) unsigned short Ps[64][72];  // masked P (bf16)

  int tid = threadIdx.x;
  size_t base = ((size_t)bh * L_ + (size_t)c * CSZ_) * HD_;
  const unsigned short* Sp = Sbuf + (size_t)bhc * 4096;
#pragma unroll
  for (int qq = 0; qq < 16; ++qq) {
    int e = tid + qq * 256;
    int r = e >> 6, col = e & 63;
    Qs[r][col] = qb[base + e];
    Ks[r][col] = kb[base + e];
    Vt[col][r] = vb[base + e];
    Sb[r][col] = Sp[e];
  }
  __syncthreads();

  int lane = tid & 63, w = tid >> 6;
  int fl = lane & 15, fh = lane >> 4;
  int rb = fh << 2;

  bf16x8 aq0 = *(const bf16x8*)(&Qs[w * 16 + fl][fh * 8]);
  bf16x8 aq1 = *(const bf16x8*)(&Qs[w * 16 + fl][32 + fh * 8]);

  f32x4 pc[4], acc[4];
#pragma unroll
  for (int jf = 0; jf < 4; ++jf) {
    bf16x8 bk0 = *(const bf16x8*)(&Ks[jf * 16 + fl][fh * 8]);
    bf16x8 bk1 = *(const bf16x8*)(&Ks[jf * 16 + fl][32 + fh * 8]);
    f32x4 z = {};
    z = __builtin_amdgcn_mfma_f32_16x16x32_bf16(aq0, bk0, z, 0, 0, 0);
    z = __builtin_amdgcn_mfma_f32_16x16x32_bf16(aq1, bk1, z, 0, 0, 0);
    pc[jf] = z;

    bf16x8 bs0 = *(const bf16x8*)(&Sb[jf * 16 + fl][fh * 8]);
    bf16x8 bs1 = *(const bf16x8*)(&Sb[jf * 16 + fl][32 + fh * 8]);
    f32x4 zz = {};
    zz = __builtin_amdgcn_mfma_f32_16x16x32_bf16(aq0, bs0, zz, 0, 0, 0);
    zz = __builtin_amdgcn_mfma_f32_16x16x32_bf16(aq1, bs1, zz, 0, 0, 0);
    acc[jf] = zz;
  }

#pragma unroll
  for (int jf = 0; jf < 4; ++jf) {
#pragma unroll
    for (int r = 0; r < 4; ++r) {
      int i = w * 16 + rb + r, j = jf * 16 + fl;
      float val = (j <= i) ? pc[jf][r] * exp2f(lg2g * (float)(i - j)) : 0.f;
      Ps[i][j] = f2bf(val);
    }
  }

  float gi1[4];
#pragma unroll
  for (int r = 0; r < 4; ++r) gi1[r] = exp2f(lg2g * (float)(w * 16 + rb + r + 1));
#pragma unroll
  for (int jf = 0; jf < 4; ++jf)
#pragma unroll
    for (int r = 0; r < 4; ++r) acc[jf][r] *= gi1[r];

  __syncthreads();

  bf16x8 ap0 = *(const bf16x8*)(&Ps[w * 16 + fl][fh * 8]);
  bf16x8 ap1 = *(const bf16x8*)(&Ps[w * 16 + fl][32 + fh * 8]);
#pragma unroll
  for (int jf = 0; jf < 4; ++jf) {
    bf16x8 bv0 = *(const bf16x8*)(&Vt[jf * 16 + fl][fh * 8]);
    bf16x8 bv1 = *(const bf16x8*)(&Vt[jf * 16 + fl][32 + fh * 8]);
    acc[jf] = __builtin_amdgcn_mfma_f32_16x16x32_bf16(ap0, bv0, acc[jf], 0, 0, 0);
    acc[jf] = __builtin_amdgcn_mfma_f32_16x16x32_bf16(ap1, bv1, acc[jf], 0, 0, 0);
  }

  size_t yrow = ((size_t)(b * L_ + c * CSZ_)) * D_ + h * HD_;
#pragma unroll
  for (int jf = 0; jf < 4; ++jf) {
#pragma unroll
    for (int r = 0; r < 4; ++r) {
      int i = w * 16 + rb + r;
      y[yrow + (size_t)i * D_ + jf * 16 + fl] = f2bf(acc[jf][r]);
    }
  }
}

// ---------------- launch ----------------
extern "C" void kernel_launch(void* const* d_in, const int* in_sizes, int n_in,
                              void* d_out, int out_size, void* d_ws, size_t ws_size,
                              hipStream_t stream)
{
  const float* x        = (const float*)d_in[0];
  const float* Wqkv_w   = (const float*)d_in[1];
  const float* Wqkv_b   = (const float*)d_in[2];
  const float* out_w    = (const float*)d_in[3];
  const float* out_b    = (const float*)d_in[4];
  const float* gamma_raw= (const float*)d_in[5];
  float* out = (float*)d_out;

  // workspace carve-up (~210 MB)
  char* ws = (char*)d_ws;
  unsigned short* x_bf    = (unsigned short*)ws; ws += (size_t)16777216 * 2;
  unsigned short* wqkv_bf = (unsigned short*)ws; ws += (size_t)3145728 * 2;
  unsigned short* wout_bf = (unsigned short*)ws; ws += (size_t)1048576 * 2;
  unsigned short* qb      = (unsigned short*)ws; ws += (size_t)16777216 * 2;
  unsigned short* kb      = (unsigned short*)ws; ws += (size_t)16777216 * 2;
  unsigned short* vb      = (unsigned short*)ws; ws += (size_t)16777216 * 2;
  unsigned short* Sbuf    = (unsigned short*)ws; ws += (size_t)16777216 * 2;
  unsigned short* yb      = (unsigned short*)ws; ws += (size_t)16777216 * 2;

  cast_kernel<<<16384, 256, 0, stream>>>(x, x_bf, 16777216);
  cast_kernel<<<3072, 256, 0, stream>>>(Wqkv_w, wqkv_bf, 3145728);
  cast_kernel<<<1024, 256, 0, stream>>>(out_w, wout_bf, 1048576);

  // qkv = x @ Wqkv^T + b  -> q/k/v (B,H,L,HD), k pre-scaled.  grid 768 (%8==0)
  gemm_pipe<0, 256, 256, 2, 4, 512><<<64 * 12, 512, 0, stream>>>(
      x_bf, wqkv_bf, Wqkv_b, qb, kb, vb, nullptr, M1_, ND3_, D_);

  ret_phase1<<<4096, 256, 0, stream>>>(kb, vb, gamma_raw, Sbuf);
  ret_phase2<<<512, 256, 0, stream>>>(Sbuf, gamma_raw);
  ret_phase3<<<4096, 256, 0, stream>>>(qb, kb, vb, Sbuf, gamma_raw, yb);

  // out = y @ out_w^T + out_b  (fp32 out).  128x128 tile, grid 1024 (%8==0), 3 blocks/CU
  gemm_pipe<1, 128, 128, 2, 2, 256><<<128 * 8, 256, 0, stream>>>(
      yb, wout_bf, out_b, nullptr, nullptr, nullptr, out, M1_, D_, D_);
}

// Round 9
// 245.750 us; speedup vs baseline: 1.3477x; 1.0415x over previous
//
#include <hip/hip_runtime.h>
#include <cstdint>
#include <cstddef>

// Problem constants
#define B_    4
#define L_    4096
#define D_    1024
#define H_    16
#define HD_   64
#define ND3_  3072          // 3*D
#define M1_   16384         // B*L
#define NCH_  64            // number of chunks
#define CSZ_  64            // chunk size
#define SCALE_ 0.125f       // 1/sqrt(HD)

typedef __attribute__((ext_vector_type(8))) __bf16 bf16x8;
typedef __attribute__((ext_vector_type(4))) float f32x4;
typedef __attribute__((ext_vector_type(16))) float f32x16;
typedef __attribute__((ext_vector_type(4))) unsigned int uint4v;

__device__ __forceinline__ float u2f(unsigned int u) { return __builtin_bit_cast(float, u); }
__device__ __forceinline__ unsigned int f2u(float f) { return __builtin_bit_cast(unsigned int, f); }
__device__ __forceinline__ float bf2f(unsigned short s) { return u2f(((unsigned int)s) << 16); }
__device__ __forceinline__ unsigned short f2bf(float f) {
  unsigned int u = f2u(f);
  u = u + 0x7fffu + ((u >> 16) & 1u);   // RNE
  return (unsigned short)(u >> 16);
}

// async global->LDS, 16B per lane. LDS dest wave-uniform base (+lane*16 implicit).
__device__ __forceinline__ void glds16(const unsigned short* g, unsigned short* l) {
  __builtin_amdgcn_global_load_lds(
      (const __attribute__((address_space(1))) void*)(uintptr_t)g,
      (__attribute__((address_space(3))) void*)(uintptr_t)l, 16, 0, 0);
}

// ---------------- fp32 -> bf16 cast ----------------
__global__ __launch_bounds__(256) void cast_kernel(const float* __restrict__ in,
                                                   unsigned short* __restrict__ out, int n)
{
  int i = (blockIdx.x * 256 + threadIdx.x) * 4;
  if (i + 3 < n) {
    float4 f = *(const float4*)(in + i);
    out[i + 0] = f2bf(f.x);
    out[i + 1] = f2bf(f.y);
    out[i + 2] = f2bf(f.z);
    out[i + 3] = f2bf(f.w);
  }
}

// ---------------- QKV GEMM: 256x256, BK=32, 32x32x16 MFMA, triple-buffer vmcnt(4) -------
// Round-9 change (isolated to QKV): MFMA shape 16x16x32 -> 32x32x16. Same LDS traffic
// (12 b128/wave/tile), half the MFMA instructions, +15% FLOP/cyc pipe rate (m06/m119).
// Sync skeleton identical to round-5/8 (proven): 1 s_barrier + counted vmcnt(4)/K-tile.
// C layout 32x32 [m74/m101]: col=lane&31, row=(reg&3)+8*(reg>>2)+4*(lane>>5).
__global__ __launch_bounds__(512, 2)
void gemm_qkv(const unsigned short* __restrict__ A, const unsigned short* __restrict__ Bm,
              const float* __restrict__ bias,
              unsigned short* __restrict__ qo, unsigned short* __restrict__ ko,
              unsigned short* __restrict__ vo, int M, int N, int K)
{
  constexpr int ASZ = 256 * 32, BSZ = 256 * 32;
  __shared__ __align__(16) unsigned short Ab[3 * ASZ];
  __shared__ __align__(16) unsigned short Bb[3 * BSZ];

  const int nwg = gridDim.x;
  const int wg = (blockIdx.x & 7) * (nwg >> 3) + (blockIdx.x >> 3);
  const int nbn = N >> 8;
  const int bm = wg / nbn, bn = wg - bm * nbn;
  const int m0 = bm << 8, n0 = bn << 8;
  const int tid = threadIdx.x;
  const int lane = tid & 63, wid = tid >> 6;
  const int wr = wid >> 2, wc = wid & 3;
  const int fl = lane & 15;
  const int l31 = lane & 31, l5 = lane >> 5;

  // staging lane constants (chunk-XOR swizzle, both sides)
  const int rowbase = wid * 16 + (lane >> 2);
  const int ckst = (lane & 3) ^ ((rowbase & 3) ^ ((rowbase >> 2) & 3));
  const int sw = (fl & 3) ^ ((fl >> 2) & 3);      // read-side swizzle for row&15 = lane&15

  const int nt = K >> 5;

  f32x16 acc[4][2] = {};

  auto stageA = [&](int kt, int d) {
#pragma unroll
    for (int s = 0; s < 2; ++s)
      glds16(A + (size_t)(m0 + s * 128 + rowbase) * K + kt * 32 + ckst * 8,
             Ab + d * ASZ + s * 128 * 32 + wid * 512);
  };
  auto stageB = [&](int kt, int d) {
#pragma unroll
    for (int s = 0; s < 2; ++s)
      glds16(Bm + (size_t)(n0 + s * 128 + rowbase) * K + kt * 32 + ckst * 8,
             Bb + d * BSZ + s * 128 * 32 + wid * 512);
  };

  // prologue: tiles 0,1 -> buffers 0,1 (8 glds/thread in flight)
  stageA(0, 0); stageB(0, 0);
  stageA(1, 1); stageB(1, 1);

  for (int t = 0; t < nt; ++t) {
    const int d = t % 3;
    if (t < nt - 1) { asm volatile("s_waitcnt vmcnt(4)" ::: "memory"); }
    else            { asm volatile("s_waitcnt vmcnt(0)" ::: "memory"); }
    __builtin_amdgcn_s_barrier();
    __builtin_amdgcn_sched_barrier(0);

    const unsigned short* Abuf = Ab + d * ASZ;
    const unsigned short* Bbuf = Bb + d * BSZ;

    // phase 0: kk=0 frags (chunk = 0*2 + l5), stage A of t+2, 8 MFMA
    {
      const int ck = (0 * 2 + l5) ^ sw;
      bf16x8 bfr[2], afr[4];
#pragma unroll
      for (int n = 0; n < 2; ++n)
        bfr[n] = *(const bf16x8*)(Bbuf + (wc * 64 + n * 32 + l31) * 32 + ck * 8);
#pragma unroll
      for (int m = 0; m < 4; ++m)
        afr[m] = *(const bf16x8*)(Abuf + (wr * 128 + m * 32 + l31) * 32 + ck * 8);
      if (t + 2 < nt) stageA(t + 2, (t + 2) % 3);
#pragma unroll
      for (int m = 0; m < 4; ++m)
#pragma unroll
        for (int n = 0; n < 2; ++n)
          acc[m][n] = __builtin_amdgcn_mfma_f32_32x32x16_bf16(afr[m], bfr[n], acc[m][n], 0, 0, 0);
    }
    // phase 1: kk=1 frags (chunk = 1*2 + l5), stage B of t+2, 8 MFMA
    {
      const int ck = (1 * 2 + l5) ^ sw;
      bf16x8 bfr[2], afr[4];
#pragma unroll
      for (int n = 0; n < 2; ++n)
        bfr[n] = *(const bf16x8*)(Bbuf + (wc * 64 + n * 32 + l31) * 32 + ck * 8);
#pragma unroll
      for (int m = 0; m < 4; ++m)
        afr[m] = *(const bf16x8*)(Abuf + (wr * 128 + m * 32 + l31) * 32 + ck * 8);
      if (t + 2 < nt) stageB(t + 2, (t + 2) % 3);
#pragma unroll
      for (int m = 0; m < 4; ++m)
#pragma unroll
        for (int n = 0; n < 2; ++n)
          acc[m][n] = __builtin_amdgcn_mfma_f32_32x32x16_bf16(afr[m], bfr[n], acc[m][n], 0, 0, 0);
    }
    __builtin_amdgcn_sched_barrier(0);
  }

  // epilogue: 32x32 C layout: row_loc = (reg&3)+8*(reg>>2)+4*l5, col_loc = l31  [m74/m101]
#pragma unroll
  for (int m = 0; m < 4; ++m) {
#pragma unroll
    for (int n = 0; n < 2; ++n) {
#pragma unroll
      for (int reg = 0; reg < 16; ++reg) {
        int row = m0 + wr * 128 + m * 32 + (reg & 3) + 8 * (reg >> 2) + 4 * l5;
        int col = n0 + wc * 64 + n * 32 + l31;
        float val = acc[m][n][reg] + bias[col];
        int which = col >> 10;          // n / 1024
        int hh = (col >> 6) & 15;       // (n/64)%16
        int hd = col & 63;
        int bb = row >> 12;             // row / L
        int tt2 = row & 4095;
        size_t idx = (((size_t)(bb * H_ + hh)) * L_ + tt2) * HD_ + hd;
        if (which == 0)      qo[idx] = f2bf(val);
        else if (which == 1) ko[idx] = f2bf(val * SCALE_);
        else                 vo[idx] = f2bf(val);
      }
    }
  }
}

// ---------------- out-proj GEMM: round-5 exact (pinned, 128x128, 16x16x32) -------------
__global__ __launch_bounds__(256, 3)
void gemm_out(const unsigned short* __restrict__ A, const unsigned short* __restrict__ Bm,
              const float* __restrict__ bias, float* __restrict__ Co, int M, int N, int K)
{
  constexpr int BM = 128, BN = 128, WM = 2, WN = 2;
  constexpr int TR = 64;              // rows per stage round (256 thr)
  constexpr int AR = BM / TR;         // 2
  constexpr int FM = BM / WM / 16;    // 4
  constexpr int FN = BN / WN / 16;    // 4
  constexpr int ASZ = BM * 32, BSZ = BN * 32;

  __shared__ __align__(16) unsigned short Ab[3 * ASZ];
  __shared__ __align__(16) unsigned short Bb[3 * BSZ];

  const int nwg = gridDim.x;
  const int wg = (blockIdx.x & 7) * (nwg >> 3) + (blockIdx.x >> 3);
  const int nbn = N / BN;
  const int bm = wg / nbn, bn = wg - bm * nbn;
  const int m0 = bm * BM, n0 = bn * BN;
  const int tid = threadIdx.x;
  const int lane = tid & 63, wid = tid >> 6;
  const int wr = wid / WN, wc = wid % WN;
  const int fl = lane & 15, fh = lane >> 4;

  const int rowbase = wid * 16 + (lane >> 2);
  const int ckst = (lane & 3) ^ ((rowbase & 3) ^ ((rowbase >> 2) & 3));
  const int ckrd = fh ^ ((fl & 3) ^ ((fl >> 2) & 3));

  const int nt = K >> 5;

  f32x4 acc[FM][FN] = {};

  auto stageA = [&](int kt, int d) {
#pragma unroll
    for (int s = 0; s < AR; ++s)
      glds16(A + (size_t)(m0 + s * TR + rowbase) * K + kt * 32 + ckst * 8,
             Ab + d * ASZ + s * TR * 32 + wid * 512);
  };
  auto stageB = [&](int kt, int d) {
#pragma unroll
    for (int s = 0; s < AR; ++s)
      glds16(Bm + (size_t)(n0 + s * TR + rowbase) * K + kt * 32 + ckst * 8,
             Bb + d * BSZ + s * TR * 32 + wid * 512);
  };

  stageA(0, 0); stageB(0, 0);
  stageA(1, 1); stageB(1, 1);

  for (int t = 0; t < nt; ++t) {
    const int d = t % 3;
    if (t < nt - 1) { asm volatile("s_waitcnt vmcnt(4)" ::: "memory"); }
    else            { asm volatile("s_waitcnt vmcnt(0)" ::: "memory"); }
    __builtin_amdgcn_s_barrier();
    __builtin_amdgcn_sched_barrier(0);

    const unsigned short* Abuf = Ab + d * ASZ;
    const unsigned short* Bbuf = Bb + d * BSZ;

    bf16x8 bfrag[FN], afrag[FM / 2];
#pragma unroll
    for (int n = 0; n < FN; ++n)
      bfrag[n] = *(const bf16x8*)(Bbuf + (wc * (BN / WN) + n * 16 + fl) * 32 + ckrd * 8);
#pragma unroll
    for (int m = 0; m < FM / 2; ++m)
      afrag[m] = *(const bf16x8*)(Abuf + (wr * (BM / WM) + m * 16 + fl) * 32 + ckrd * 8);
    if (t + 2 < nt) stageA(t + 2, (t + 2) % 3);
    asm volatile("s_waitcnt lgkmcnt(0)" ::: "memory");
    __builtin_amdgcn_sched_barrier(0);
    __builtin_amdgcn_s_setprio(1);
#pragma unroll
    for (int m = 0; m < FM / 2; ++m)
#pragma unroll
      for (int n = 0; n < FN; ++n)
        acc[m][n] = __builtin_amdgcn_mfma_f32_16x16x32_bf16(afrag[m], bfrag[n], acc[m][n], 0, 0, 0);
    __builtin_amdgcn_s_setprio(0);

    bf16x8 afrag2[FM / 2];
#pragma unroll
    for (int m = 0; m < FM / 2; ++m)
      afrag2[m] = *(const bf16x8*)(Abuf + (wr * (BM / WM) + (m + FM / 2) * 16 + fl) * 32 + ckrd * 8);
    if (t + 2 < nt) stageB(t + 2, (t + 2) % 3);
    asm volatile("s_waitcnt lgkmcnt(0)" ::: "memory");
    __builtin_amdgcn_sched_barrier(0);
    __builtin_amdgcn_s_setprio(1);
#pragma unroll
    for (int m = 0; m < FM / 2; ++m)
#pragma unroll
      for (int n = 0; n < FN; ++n)
        acc[m + FM / 2][n] = __builtin_amdgcn_mfma_f32_16x16x32_bf16(afrag2[m], bfrag[n], acc[m + FM / 2][n], 0, 0, 0);
    __builtin_amdgcn_s_setprio(0);
  }

  const int rb = fh << 2;
#pragma unroll
  for (int m = 0; m < FM; ++m)
#pragma unroll
    for (int n = 0; n < FN; ++n)
#pragma unroll
      for (int r = 0; r < 4; ++r) {
        int row = m0 + wr * (BM / WM) + m * 16 + rb + r;
        int col = n0 + wc * (BN / WN) + n * 16 + fl;
        Co[(size_t)row * N + col] = acc[m][n][r] + bias[col];
      }
}

// ---------------- retention phase 1 (MFMA): A_c[a][b] = sum_j g^{63-j} v_j[a] k_j[b] ----------------
__global__ __launch_bounds__(256) void ret_phase1(
    const unsigned short* __restrict__ kb, const unsigned short* __restrict__ vb,
    const float* __restrict__ gamma_raw, unsigned short* __restrict__ Sbuf)
{
  int bhc = blockIdx.x;
  int c = bhc & 63, bh = bhc >> 6, h = bh & 15;
  float g = 1.f / (1.f + expf(-gamma_raw[h]));
  float lg2g = log2f(g);

  __shared__ __align__(16) unsigned short Kt[64][72];   // Kt[b][j] = K[j][b]
  __shared__ __align__(16) unsigned short Vwt[64][72];  // Vwt[a][j] = g^{63-j} V[j][a]

  int tid = threadIdx.x;
  size_t base = ((size_t)bh * L_ + (size_t)c * CSZ_) * HD_;
#pragma unroll
  for (int qq = 0; qq < 16; ++qq) {
    int e = tid + qq * 256;
    int j = e >> 6, col = e & 63;
    float wj = exp2f(lg2g * (float)(63 - j));
    Kt[col][j] = kb[base + e];
    Vwt[col][j] = f2bf(bf2f(vb[base + e]) * wj);
  }
  __syncthreads();

  int lane = tid & 63, w = tid >> 6;
  int fl = lane & 15, fh = lane >> 4;

  bf16x8 av0 = *(const bf16x8*)(&Vwt[w * 16 + fl][fh * 8]);
  bf16x8 av1 = *(const bf16x8*)(&Vwt[w * 16 + fl][32 + fh * 8]);

  int rb = fh << 2;
  unsigned short* out = Sbuf + (size_t)bhc * 4096;
#pragma unroll
  for (int jf = 0; jf < 4; ++jf) {
    bf16x8 bk0 = *(const bf16x8*)(&Kt[jf * 16 + fl][fh * 8]);
    bf16x8 bk1 = *(const bf16x8*)(&Kt[jf * 16 + fl][32 + fh * 8]);
    f32x4 z = {};
    z = __builtin_amdgcn_mfma_f32_16x16x32_bf16(av0, bk0, z, 0, 0, 0);
    z = __builtin_amdgcn_mfma_f32_16x16x32_bf16(av1, bk1, z, 0, 0, 0);
#pragma unroll
    for (int r = 0; r < 4; ++r) {
      int a = w * 16 + rb + r, bcol = jf * 16 + fl;
      out[a * 64 + bcol] = f2bf(z[r]);
    }
  }
}

// ---------------- retention phase 2: in-place decay scan over chunks (bf16 storage) ----------------
__global__ __launch_bounds__(256) void ret_phase2(unsigned short* __restrict__ Sbuf,
                                                  const float* __restrict__ gamma_raw)
{
  int bh = blockIdx.x >> 3, grp = blockIdx.x & 7;
  int h = bh & 15;
  float g = 1.f / (1.f + expf(-gamma_raw[h]));
  float gC = powf(g, 64.f);
  int e = (grp * 256 + threadIdx.x) * 2;
  unsigned short* base = Sbuf + (size_t)bh * (NCH_ * 4096) + e;
  float s0 = 0.f, s1 = 0.f;
  for (int c = 0; c < NCH_; ++c) {
    unsigned int u = *(unsigned int*)(base + (size_t)c * 4096);
    float a0 = bf2f((unsigned short)(u & 0xffffu));
    float a1 = bf2f((unsigned short)(u >> 16));
    *(unsigned int*)(base + (size_t)c * 4096) =
        (unsigned int)f2bf(s0) | ((unsigned int)f2bf(s1) << 16);
    s0 = gC * s0 + a0;
    s1 = gC * s1 + a1;
  }
}

// ---------------- retention phase 3 (MFMA): Y = (D ∘ QK^T) V + g^{i+1} (Q S^T) ----------------
__global__ __launch_bounds__(256) void ret_phase3(
    const unsigned short* __restrict__ qb, const unsigned short* __restrict__ kb,
    const unsigned short* __restrict__ vb, const unsigned short* __restrict__ Sbuf,
    const float* __restrict__ gamma_raw, unsigned short* __restrict__ y)
{
  int bhc = blockIdx.x;
  int c = bhc & 63, bh = bhc >> 6, h = bh & 15, b = bh >> 4;
  float g = 1.f / (1.f + expf(-gamma_raw[h]));
  float lg2g = log2f(g);

  __shared__ __align__(16) unsigned short Qs[64][72];
  __shared__ __align__(16) unsigned short Ks[64][72];
  __shared__ __align__(16) unsigned short Vt[64][72];  // Vt[a][j] = V[j][a]
  __shared__ __align__(16) unsigned short Sb[64][72];  // S rows (bf16)
  __shared__ __align__(16) unsigned short Ps[64][72];  // masked P (bf16)

  int tid = threadIdx.x;
  size_t base = ((size_t)bh * L_ + (size_t)c * CSZ_) * HD_;
  const unsigned short* Sp = Sbuf + (size_t)bhc * 4096;
#pragma unroll
  for (int qq = 0; qq < 16; ++qq) {
    int e = tid + qq * 256;
    int r = e >> 6, col = e & 63;
    Qs[r][col] = qb[base + e];
    Ks[r][col] = kb[base + e];
    Vt[col][r] = vb[base + e];
    Sb[r][col] = Sp[e];
  }
  __syncthreads();

  int lane = tid & 63, w = tid >> 6;
  int fl = lane & 15, fh = lane >> 4;
  int rb = fh << 2;

  bf16x8 aq0 = *(const bf16x8*)(&Qs[w * 16 + fl][fh * 8]);
  bf16x8 aq1 = *(const bf16x8*)(&Qs[w * 16 + fl][32 + fh * 8]);

  f32x4 pc[4], acc[4];
#pragma unroll
  for (int jf = 0; jf < 4; ++jf) {
    bf16x8 bk0 = *(const bf16x8*)(&Ks[jf * 16 + fl][fh * 8]);
    bf16x8 bk1 = *(const bf16x8*)(&Ks[jf * 16 + fl][32 + fh * 8]);
    f32x4 z = {};
    z = __builtin_amdgcn_mfma_f32_16x16x32_bf16(aq0, bk0, z, 0, 0, 0);
    z = __builtin_amdgcn_mfma_f32_16x16x32_bf16(aq1, bk1, z, 0, 0, 0);
    pc[jf] = z;

    bf16x8 bs0 = *(const bf16x8*)(&Sb[jf * 16 + fl][fh * 8]);
    bf16x8 bs1 = *(const bf16x8*)(&Sb[jf * 16 + fl][32 + fh * 8]);
    f32x4 zz = {};
    zz = __builtin_amdgcn_mfma_f32_16x16x32_bf16(aq0, bs0, zz, 0, 0, 0);
    zz = __builtin_amdgcn_mfma_f32_16x16x32_bf16(aq1, bs1, zz, 0, 0, 0);
    acc[jf] = zz;
  }

#pragma unroll
  for (int jf = 0; jf < 4; ++jf) {
#pragma unroll
    for (int r = 0; r < 4; ++r) {
      int i = w * 16 + rb + r, j = jf * 16 + fl;
      float val = (j <= i) ? pc[jf][r] * exp2f(lg2g * (float)(i - j)) : 0.f;
      Ps[i][j] = f2bf(val);
    }
  }

  float gi1[4];
#pragma unroll
  for (int r = 0; r < 4; ++r) gi1[r] = exp2f(lg2g * (float)(w * 16 + rb + r + 1));
#pragma unroll
  for (int jf = 0; jf < 4; ++jf)
#pragma unroll
    for (int r = 0; r < 4; ++r) acc[jf][r] *= gi1[r];

  __syncthreads();

  bf16x8 ap0 = *(const bf16x8*)(&Ps[w * 16 + fl][fh * 8]);
  bf16x8 ap1 = *(const bf16x8*)(&Ps[w * 16 + fl][32 + fh * 8]);
#pragma unroll
  for (int jf = 0; jf < 4; ++jf) {
    bf16x8 bv0 = *(const bf16x8*)(&Vt[jf * 16 + fl][fh * 8]);
    bf16x8 bv1 = *(const bf16x8*)(&Vt[jf * 16 + fl][32 + fh * 8]);
    acc[jf] = __builtin_amdgcn_mfma_f32_16x16x32_bf16(ap0, bv0, acc[jf], 0, 0, 0);
    acc[jf] = __builtin_amdgcn_mfma_f32_16x16x32_bf16(ap1, bv1, acc[jf], 0, 0, 0);
  }

  size_t yrow = ((size_t)(b * L_ + c * CSZ_)) * D_ + h * HD_;
#pragma unroll
  for (int jf = 0; jf < 4; ++jf) {
#pragma unroll
    for (int r = 0; r < 4; ++r) {
      int i = w * 16 + rb + r;
      y[yrow + (size_t)i * D_ + jf * 16 + fl] = f2bf(acc[jf][r]);
    }
  }
}

// ---------------- launch ----------------
extern "C" void kernel_launch(void* const* d_in, const int* in_sizes, int n_in,
                              void* d_out, int out_size, void* d_ws, size_t ws_size,
                              hipStream_t stream)
{
  const float* x        = (const float*)d_in[0];
  const float* Wqkv_w   = (const float*)d_in[1];
  const float* Wqkv_b   = (const float*)d_in[2];
  const float* out_w    = (const float*)d_in[3];
  const float* out_b    = (const float*)d_in[4];
  const float* gamma_raw= (const float*)d_in[5];
  float* out = (float*)d_out;

  // workspace carve-up (~210 MB)
  char* ws = (char*)d_ws;
  unsigned short* x_bf    = (unsigned short*)ws; ws += (size_t)16777216 * 2;
  unsigned short* wqkv_bf = (unsigned short*)ws; ws += (size_t)3145728 * 2;
  unsigned short* wout_bf = (unsigned short*)ws; ws += (size_t)1048576 * 2;
  unsigned short* qb      = (unsigned short*)ws; ws += (size_t)16777216 * 2;
  unsigned short* kb      = (unsigned short*)ws; ws += (size_t)16777216 * 2;
  unsigned short* vb      = (unsigned short*)ws; ws += (size_t)16777216 * 2;
  unsigned short* Sbuf    = (unsigned short*)ws; ws += (size_t)16777216 * 2;
  unsigned short* yb      = (unsigned short*)ws; ws += (size_t)16777216 * 2;

  cast_kernel<<<16384, 256, 0, stream>>>(x, x_bf, 16777216);
  cast_kernel<<<3072, 256, 0, stream>>>(Wqkv_w, wqkv_bf, 3145728);
  cast_kernel<<<1024, 256, 0, stream>>>(out_w, wout_bf, 1048576);

  // qkv = x @ Wqkv^T + b  -> q/k/v (B,H,L,HD), k pre-scaled.  grid 768 (%8==0)
  gemm_qkv<<<64 * 12, 512, 0, stream>>>(x_bf, wqkv_bf, Wqkv_b,
                                        qb, kb, vb, M1_, ND3_, D_);

  ret_phase1<<<4096, 256, 0, stream>>>(kb, vb, gamma_raw, Sbuf);
  ret_phase2<<<512, 256, 0, stream>>>(Sbuf, gamma_raw);
  ret_phase3<<<4096, 256, 0, stream>>>(qb, kb, vb, Sbuf, gamma_raw, yb);

  // out = y @ out_w^T + out_b  (fp32 out).  round-5 pinned 128x128, grid 1024, 3 blk/CU
  gemm_out<<<128 * 8, 256, 0, stream>>>(yb, wout_bf, out_b, out, M1_, D_, D_);
}

// Round 11
// 242.641 us; speedup vs baseline: 1.3649x; 1.0128x over previous
//
#include <hip/hip_runtime.h>
#include <cstdint>
#include <cstddef>

// Problem constants
#define B_    4
#define L_    4096
#define D_    1024
#define H_    16
#define HD_   64
#define ND3_  3072          // 3*D
#define M1_   16384         // B*L
#define NCH_  64            // number of chunks
#define CSZ_  64            // chunk size
#define SCALE_ 0.125f       // 1/sqrt(HD)

typedef __attribute__((ext_vector_type(8))) __bf16 bf16x8;
typedef __attribute__((ext_vector_type(4))) float f32x4;
typedef __attribute__((ext_vector_type(4))) unsigned int uint4v;

__device__ __forceinline__ float u2f(unsigned int u) { return __builtin_bit_cast(float, u); }
__device__ __forceinline__ unsigned int f2u(float f) { return __builtin_bit_cast(unsigned int, f); }
__device__ __forceinline__ float bf2f(unsigned short s) { return u2f(((unsigned int)s) << 16); }
__device__ __forceinline__ unsigned short f2bf(float f) {
  unsigned int u = f2u(f);
  u = u + 0x7fffu + ((u >> 16) & 1u);   // RNE
  return (unsigned short)(u >> 16);
}

// async global->LDS, 16B per lane. LDS dest wave-uniform base (+lane*16 implicit).
__device__ __forceinline__ void glds16(const unsigned short* g, unsigned short* l) {
  __builtin_amdgcn_global_load_lds(
      (const __attribute__((address_space(1))) void*)(uintptr_t)g,
      (__attribute__((address_space(3))) void*)(uintptr_t)l, 16, 0, 0);
}

// ---------------- fp32 -> bf16 cast ----------------
__global__ __launch_bounds__(256) void cast_kernel(const float* __restrict__ in,
                                                   unsigned short* __restrict__ out, int n)
{
  int i = (blockIdx.x * 256 + threadIdx.x) * 4;
  if (i + 3 < n) {
    float4 f = *(const float4*)(in + i);
    out[i + 0] = f2bf(f.x);
    out[i + 1] = f2bf(f.y);
    out[i + 2] = f2bf(f.z);
    out[i + 3] = f2bf(f.w);
  }
}

// ---------------- QKV GEMM: 256x256, BK=64, 8-phase (m201-style port) ------------------
// 8 waves (2Mx4N). Per-wave C 128x64 split into 4 quadrants INTERLEAVED across halves:
// rows = mh*128 + wr*64 + [0,64), cols = nh*128 + wc*32 + [0,32)  -> phase (mh,nh) reads
// exactly A-half{mh}, B-half{nh} for ALL waves. LDS = 2 dbuf x {A,B} x 2 half x 128x64
// bf16 = 128 KB. Per phase: {ds_read frags || stage 1 half-tile (2 glds) || s_barrier ||
// lgkmcnt(0) || setprio(1) 16 MFMA setprio(0) || s_barrier}. Staging schedule during
// tile t: p1:A1(t+1) p2:B1(t+1) p3:B0(t+2) p4:A0(t+2)  (each slot's last read is >=1
// barrier earlier). ONE counted vmcnt(4) per K-tile at p4-end: drains all but newest 2
// halves => entire tile t+1 landed; t>=nt-2 -> vmcnt(0).
// ROUND-11 FIX: s_barrier after prologue vmcnt(4). vmcnt is PER-WAVE; without a barrier
// a fast wave's tile-0 ds_read races other waves' cooperative glds (the r10 absmax-0.56
// failure). Steady-state tile boundaries already have vmcnt+barrier; prologue now matches.
__global__ __launch_bounds__(512, 2)
void gemm_qkv8(const unsigned short* __restrict__ A, const unsigned short* __restrict__ Bm,
               const float* __restrict__ bias,
               unsigned short* __restrict__ qo, unsigned short* __restrict__ ko,
               unsigned short* __restrict__ vo, int M, int N, int K)
{
  __shared__ __align__(16) unsigned short Ab[2 * 2 * 8192];  // [dbuf][half][128][64]
  __shared__ __align__(16) unsigned short Bb[2 * 2 * 8192];

  const int nwg = gridDim.x;
  const int wg = (blockIdx.x & 7) * (nwg >> 3) + (blockIdx.x >> 3);
  const int nbn = N >> 8;
  const int bm = wg / nbn, bn = wg - bm * nbn;
  const int m0 = bm << 8, n0 = bn << 8;
  const int tid = threadIdx.x;
  const int lane = tid & 63, wid = tid >> 6;
  const int wr = wid >> 2, wc = wid & 3;        // 2 x 4 wave grid
  const int fl = lane & 15, fh = lane >> 4;
  const int swz = fl & 7;

  const int nt = K >> 6;                        // 16 K-tiles of BK=64

  // staging lane constants: 1 glds = 8 rows x 8 chunks x 16B; phys chunk = lane&7,
  // row-in-stripe = lane>>3, logical chunk = phys ^ (row&7)
  const int srow = lane >> 3;
  const int slc = (lane & 7) ^ srow;

  f32x4 acc[2][2][4][2] = {};   // [mh][nh][m][n]

  auto stage = [&](const unsigned short* Mat, int rbase, int h, int kt,
                   unsigned short* buf) {
    const int d = kt & 1;
#pragma unroll
    for (int s = 0; s < 2; ++s) {
      const int rl = (wid * 2 + s) * 8 + srow;
      glds16(Mat + (size_t)(rbase + h * 128 + rl) * K + kt * 64 + slc * 8,
             buf + (d * 2 + h) * 8192 + (wid * 2 + s) * 512);
    }
  };

  // prologue: tile0 {A0,B0,A1,B1}, then tile1 {B0,A0}; vmcnt(4) leaves tile1's 2 halves
  stage(A, m0, 0, 0, Ab); stage(Bm, n0, 0, 0, Bb);
  stage(A, m0, 1, 0, Ab); stage(Bm, n0, 1, 0, Bb);
  stage(Bm, n0, 0, 1, Bb); stage(A, m0, 0, 1, Ab);
  asm volatile("s_waitcnt vmcnt(4)" ::: "memory");
  __builtin_amdgcn_s_barrier();        // r11 FIX: all waves' tile-0 DMA visible to all
  __builtin_amdgcn_sched_barrier(0);

  for (int t = 0; t < nt; ++t) {
    const int d = t & 1;
    const unsigned short* Abuf = Ab + d * 16384;
    const unsigned short* Bbuf = Bb + d * 16384;
    bf16x8 af0[4][2], af1[4][2], bf0[2][2], bf1[2][2];

    // ---- phase 1: quadrant (0,0); reads A-half0 + B-half0; stage A1(t+1) ----
#pragma unroll
    for (int m = 0; m < 4; ++m)
#pragma unroll
      for (int ks = 0; ks < 2; ++ks)
        af0[m][ks] = *(const bf16x8*)(Abuf + (wr * 64 + m * 16 + fl) * 64 + ((ks * 4 + fh) ^ swz) * 8);
#pragma unroll
    for (int n = 0; n < 2; ++n)
#pragma unroll
      for (int ks = 0; ks < 2; ++ks)
        bf0[n][ks] = *(const bf16x8*)(Bbuf + (wc * 32 + n * 16 + fl) * 64 + ((ks * 4 + fh) ^ swz) * 8);
    if (t + 1 < nt) stage(A, m0, 1, t + 1, Ab);
    __builtin_amdgcn_s_barrier();
    asm volatile("s_waitcnt lgkmcnt(0)" ::: "memory");
    __builtin_amdgcn_sched_barrier(0);
    __builtin_amdgcn_s_setprio(1);
#pragma unroll
    for (int m = 0; m < 4; ++m)
#pragma unroll
      for (int n = 0; n < 2; ++n)
#pragma unroll
        for (int ks = 0; ks < 2; ++ks)
          acc[0][0][m][n] = __builtin_amdgcn_mfma_f32_16x16x32_bf16(af0[m][ks], bf0[n][ks], acc[0][0][m][n], 0, 0, 0);
    __builtin_amdgcn_s_setprio(0);
    __builtin_amdgcn_s_barrier();

    // ---- phase 2: quadrant (1,0); reads A-half1 (B-half0 from regs); stage B1(t+1) ----
#pragma unroll
    for (int m = 0; m < 4; ++m)
#pragma unroll
      for (int ks = 0; ks < 2; ++ks)
        af1[m][ks] = *(const bf16x8*)(Abuf + 8192 + (wr * 64 + m * 16 + fl) * 64 + ((ks * 4 + fh) ^ swz) * 8);
    if (t + 1 < nt) stage(Bm, n0, 1, t + 1, Bb);
    __builtin_amdgcn_s_barrier();
    asm volatile("s_waitcnt lgkmcnt(0)" ::: "memory");
    __builtin_amdgcn_sched_barrier(0);
    __builtin_amdgcn_s_setprio(1);
#pragma unroll
    for (int m = 0; m < 4; ++m)
#pragma unroll
      for (int n = 0; n < 2; ++n)
#pragma unroll
        for (int ks = 0; ks < 2; ++ks)
          acc[1][0][m][n] = __builtin_amdgcn_mfma_f32_16x16x32_bf16(af1[m][ks], bf0[n][ks], acc[1][0][m][n], 0, 0, 0);
    __builtin_amdgcn_s_setprio(0);
    __builtin_amdgcn_s_barrier();

    // ---- phase 3: quadrant (0,1); reads B-half1 (A-half0 from regs); stage B0(t+2) ----
#pragma unroll
    for (int n = 0; n < 2; ++n)
#pragma unroll
      for (int ks = 0; ks < 2; ++ks)
        bf1[n][ks] = *(const bf16x8*)(Bbuf + 8192 + (wc * 32 + n * 16 + fl) * 64 + ((ks * 4 + fh) ^ swz) * 8);
    if (t + 2 < nt) stage(Bm, n0, 0, t + 2, Bb);
    __builtin_amdgcn_s_barrier();
    asm volatile("s_waitcnt lgkmcnt(0)" ::: "memory");
    __builtin_amdgcn_sched_barrier(0);
    __builtin_amdgcn_s_setprio(1);
#pragma unroll
    for (int m = 0; m < 4; ++m)
#pragma unroll
      for (int n = 0; n < 2; ++n)
#pragma unroll
        for (int ks = 0; ks < 2; ++ks)
          acc[0][1][m][n] = __builtin_amdgcn_mfma_f32_16x16x32_bf16(af0[m][ks], bf1[n][ks], acc[0][1][m][n], 0, 0, 0);
    __builtin_amdgcn_s_setprio(0);
    __builtin_amdgcn_s_barrier();

    // ---- phase 4: quadrant (1,1); all from regs; stage A0(t+2); per-tile vmcnt ----
    if (t + 2 < nt) stage(A, m0, 0, t + 2, Ab);
    __builtin_amdgcn_s_setprio(1);
#pragma unroll
    for (int m = 0; m < 4; ++m)
#pragma unroll
      for (int n = 0; n < 2; ++n)
#pragma unroll
        for (int ks = 0; ks < 2; ++ks)
          acc[1][1][m][n] = __builtin_amdgcn_mfma_f32_16x16x32_bf16(af1[m][ks], bf1[n][ks], acc[1][1][m][n], 0, 0, 0);
    __builtin_amdgcn_s_setprio(0);
    if (t < nt - 2) { asm volatile("s_waitcnt vmcnt(4)" ::: "memory"); }
    else            { asm volatile("s_waitcnt vmcnt(0)" ::: "memory"); }
    __builtin_amdgcn_s_barrier();
    __builtin_amdgcn_sched_barrier(0);
  }

  // epilogue: 16x16 C layout [m89]: row_loc = fh*4 + r, col_loc = fl
  const int rb = fh << 2;
#pragma unroll
  for (int mh = 0; mh < 2; ++mh) {
#pragma unroll
    for (int nh = 0; nh < 2; ++nh) {
#pragma unroll
      for (int m = 0; m < 4; ++m) {
#pragma unroll
        for (int n = 0; n < 2; ++n) {
#pragma unroll
          for (int r = 0; r < 4; ++r) {
            int row = m0 + mh * 128 + wr * 64 + m * 16 + rb + r;
            int col = n0 + nh * 128 + wc * 32 + n * 16 + fl;
            float val = acc[mh][nh][m][n][r] + bias[col];
            int which = col >> 10;          // n / 1024
            int hh = (col >> 6) & 15;       // (n/64)%16
            int hd = col & 63;
            int bb = row >> 12;             // row / L
            int tt2 = row & 4095;
            size_t idx = (((size_t)(bb * H_ + hh)) * L_ + tt2) * HD_ + hd;
            if (which == 0)      qo[idx] = f2bf(val);
            else if (which == 1) ko[idx] = f2bf(val * SCALE_);
            else                 vo[idx] = f2bf(val);
          }
        }
      }
    }
  }
}

// ---------------- out-proj GEMM: round-5 exact (pinned, 128x128, 16x16x32) -------------
__global__ __launch_bounds__(256, 3)
void gemm_out(const unsigned short* __restrict__ A, const unsigned short* __restrict__ Bm,
              const float* __restrict__ bias, float* __restrict__ Co, int M, int N, int K)
{
  constexpr int BM = 128, BN = 128, WM = 2, WN = 2;
  constexpr int TR = 64;
  constexpr int AR = BM / TR;
  constexpr int FM = BM / WM / 16;
  constexpr int FN = BN / WN / 16;
  constexpr int ASZ = BM * 32, BSZ = BN * 32;

  __shared__ __align__(16) unsigned short Ab[3 * ASZ];
  __shared__ __align__(16) unsigned short Bb[3 * BSZ];

  const int nwg = gridDim.x;
  const int wg = (blockIdx.x & 7) * (nwg >> 3) + (blockIdx.x >> 3);
  const int nbn = N / BN;
  const int bm = wg / nbn, bn = wg - bm * nbn;
  const int m0 = bm * BM, n0 = bn * BN;
  const int tid = threadIdx.x;
  const int lane = tid & 63, wid = tid >> 6;
  const int wr = wid / WN, wc = wid % WN;
  const int fl = lane & 15, fh = lane >> 4;

  const int rowbase = wid * 16 + (lane >> 2);
  const int ckst = (lane & 3) ^ ((rowbase & 3) ^ ((rowbase >> 2) & 3));
  const int ckrd = fh ^ ((fl & 3) ^ ((fl >> 2) & 3));

  const int nt = K >> 5;

  f32x4 acc[FM][FN] = {};

  auto stageA = [&](int kt, int d) {
#pragma unroll
    for (int s = 0; s < AR; ++s)
      glds16(A + (size_t)(m0 + s * TR + rowbase) * K + kt * 32 + ckst * 8,
             Ab + d * ASZ + s * TR * 32 + wid * 512);
  };
  auto stageB = [&](int kt, int d) {
#pragma unroll
    for (int s = 0; s < AR; ++s)
      glds16(Bm + (size_t)(n0 + s * TR + rowbase) * K + kt * 32 + ckst * 8,
             Bb + d * BSZ + s * TR * 32 + wid * 512);
  };

  stageA(0, 0); stageB(0, 0);
  stageA(1, 1); stageB(1, 1);

  for (int t = 0; t < nt; ++t) {
    const int d = t % 3;
    if (t < nt - 1) { asm volatile("s_waitcnt vmcnt(4)" ::: "memory"); }
    else            { asm volatile("s_waitcnt vmcnt(0)" ::: "memory"); }
    __builtin_amdgcn_s_barrier();
    __builtin_amdgcn_sched_barrier(0);

    const unsigned short* Abuf = Ab + d * ASZ;
    const unsigned short* Bbuf = Bb + d * BSZ;

    bf16x8 bfrag[FN], afrag[FM / 2];
#pragma unroll
    for (int n = 0; n < FN; ++n)
      bfrag[n] = *(const bf16x8*)(Bbuf + (wc * (BN / WN) + n * 16 + fl) * 32 + ckrd * 8);
#pragma unroll
    for (int m = 0; m < FM / 2; ++m)
      afrag[m] = *(const bf16x8*)(Abuf + (wr * (BM / WM) + m * 16 + fl) * 32 + ckrd * 8);
    if (t + 2 < nt) stageA(t + 2, (t + 2) % 3);
    asm volatile("s_waitcnt lgkmcnt(0)" ::: "memory");
    __builtin_amdgcn_sched_barrier(0);
    __builtin_amdgcn_s_setprio(1);
#pragma unroll
    for (int m = 0; m < FM / 2; ++m)
#pragma unroll
      for (int n = 0; n < FN; ++n)
        acc[m][n] = __builtin_amdgcn_mfma_f32_16x16x32_bf16(afrag[m], bfrag[n], acc[m][n], 0, 0, 0);
    __builtin_amdgcn_s_setprio(0);

    bf16x8 afrag2[FM / 2];
#pragma unroll
    for (int m = 0; m < FM / 2; ++m)
      afrag2[m] = *(const bf16x8*)(Abuf + (wr * (BM / WM) + (m + FM / 2) * 16 + fl) * 32 + ckrd * 8);
    if (t + 2 < nt) stageB(t + 2, (t + 2) % 3);
    asm volatile("s_waitcnt lgkmcnt(0)" ::: "memory");
    __builtin_amdgcn_sched_barrier(0);
    __builtin_amdgcn_s_setprio(1);
#pragma unroll
    for (int m = 0; m < FM / 2; ++m)
#pragma unroll
      for (int n = 0; n < FN; ++n)
        acc[m + FM / 2][n] = __builtin_amdgcn_mfma_f32_16x16x32_bf16(afrag2[m], bfrag[n], acc[m + FM / 2][n], 0, 0, 0);
    __builtin_amdgcn_s_setprio(0);
  }

  const int rb = fh << 2;
#pragma unroll
  for (int m = 0; m < FM; ++m)
#pragma unroll
    for (int n = 0; n < FN; ++n)
#pragma unroll
      for (int r = 0; r < 4; ++r) {
        int row = m0 + wr * (BM / WM) + m * 16 + rb + r;
        int col = n0 + wc * (BN / WN) + n * 16 + fl;
        Co[(size_t)row * N + col] = acc[m][n][r] + bias[col];
      }
}

// ---------------- retention phase 1 (MFMA): A_c[a][b] = sum_j g^{63-j} v_j[a] k_j[b] ----------------
__global__ __launch_bounds__(256) void ret_phase1(
    const unsigned short* __restrict__ kb, const unsigned short* __restrict__ vb,
    const float* __restrict__ gamma_raw, unsigned short* __restrict__ Sbuf)
{
  int bhc = blockIdx.x;
  int c = bhc & 63, bh = bhc >> 6, h = bh & 15;
  float g = 1.f / (1.f + expf(-gamma_raw[h]));
  float lg2g = log2f(g);

  __shared__ __align__(16) unsigned short Kt[64][72];
  __shared__ __align__(16) unsigned short Vwt[64][72];

  int tid = threadIdx.x;
  size_t base = ((size_t)bh * L_ + (size_t)c * CSZ_) * HD_;
#pragma unroll
  for (int qq = 0; qq < 16; ++qq) {
    int e = tid + qq * 256;
    int j = e >> 6, col = e & 63;
    float wj = exp2f(lg2g * (float)(63 - j));
    Kt[col][j] = kb[base + e];
    Vwt[col][j] = f2bf(bf2f(vb[base + e]) * wj);
  }
  __syncthreads();

  int lane = tid & 63, w = tid >> 6;
  int fl = lane & 15, fh = lane >> 4;

  bf16x8 av0 = *(const bf16x8*)(&Vwt[w * 16 + fl][fh * 8]);
  bf16x8 av1 = *(const bf16x8*)(&Vwt[w * 16 + fl][32 + fh * 8]);

  int rb = fh << 2;
  unsigned short* out = Sbuf + (size_t)bhc * 4096;
#pragma unroll
  for (int jf = 0; jf < 4; ++jf) {
    bf16x8 bk0 = *(const bf16x8*)(&Kt[jf * 16 + fl][fh * 8]);
    bf16x8 bk1 = *(const bf16x8*)(&Kt[jf * 16 + fl][32 + fh * 8]);
    f32x4 z = {};
    z = __builtin_amdgcn_mfma_f32_16x16x32_bf16(av0, bk0, z, 0, 0, 0);
    z = __builtin_amdgcn_mfma_f32_16x16x32_bf16(av1, bk1, z, 0, 0, 0);
#pragma unroll
    for (int r = 0; r < 4; ++r) {
      int a = w * 16 + rb + r, bcol = jf * 16 + fl;
      out[a * 64 + bcol] = f2bf(z[r]);
    }
  }
}

// ---------------- retention phase 2: in-place decay scan over chunks (bf16 storage) ----------------
__global__ __launch_bounds__(256) void ret_phase2(unsigned short* __restrict__ Sbuf,
                                                  const float* __restrict__ gamma_raw)
{
  int bh = blockIdx.x >> 3, grp = blockIdx.x & 7;
  int h = bh & 15;
  float g = 1.f / (1.f + expf(-gamma_raw[h]));
  float gC = powf(g, 64.f);
  int e = (grp * 256 + threadIdx.x) * 2;
  unsigned short* base = Sbuf + (size_t)bh * (NCH_ * 4096) + e;
  float s0 = 0.f, s1 = 0.f;
  for (int c = 0; c < NCH_; ++c) {
    unsigned int u = *(unsigned int*)(base + (size_t)c * 4096);
    float a0 = bf2f((unsigned short)(u & 0xffffu));
    float a1 = bf2f((unsigned short)(u >> 16));
    *(unsigned int*)(base + (size_t)c * 4096) =
        (unsigned int)f2bf(s0) | ((unsigned int)f2bf(s1) << 16);
    s0 = gC * s0 + a0;
    s1 = gC * s1 + a1;
  }
}

// ---------------- retention phase 3 (MFMA): Y = (D ∘ QK^T) V + g^{i+1} (Q S^T) ----------------
__global__ __launch_bounds__(256) void ret_phase3(
    const unsigned short* __restrict__ qb, const unsigned short* __restrict__ kb,
    const unsigned short* __restrict__ vb, const unsigned short* __restrict__ Sbuf,
    const float* __restrict__ gamma_raw, unsigned short* __restrict__ y)
{
  int bhc = blockIdx.x;
  int c = bhc & 63, bh = bhc >> 6, h = bh & 15, b = bh >> 4;
  float g = 1.f / (1.f + expf(-gamma_raw[h]));
  float lg2g = log2f(g);

  __shared__ __align__(16) unsigned short Qs[64][72];
  __shared__ __align__(16) unsigned short Ks[64][72];
  __shared__ __align__(16) unsigned short Vt[64][72];
  __shared__ __align__(16) unsigned short Sb[64][72];
  __shared__ __align__(16) unsigned short Ps[64][72];

  int tid = threadIdx.x;
  size_t base = ((size_t)bh * L_ + (size_t)c * CSZ_) * HD_;
  const unsigned short* Sp = Sbuf + (size_t)bhc * 4096;
#pragma unroll
  for (int qq = 0; qq < 16; ++qq) {
    int e = tid + qq * 256;
    int r = e >> 6, col = e & 63;
    Qs[r][col] = qb[base + e];
    Ks[r][col] = kb[base + e];
    Vt[col][r] = vb[base + e];
    Sb[r][col] = Sp[e];
  }
  __syncthreads();

  int lane = tid & 63, w = tid >> 6;
  int fl = lane & 15, fh = lane >> 4;
  int rb = fh << 2;

  bf16x8 aq0 = *(const bf16x8*)(&Qs[w * 16 + fl][fh * 8]);
  bf16x8 aq1 = *(const bf16x8*)(&Qs[w * 16 + fl][32 + fh * 8]);

  f32x4 pc[4], acc[4];
#pragma unroll
  for (int jf = 0; jf < 4; ++jf) {
    bf16x8 bk0 = *(const bf16x8*)(&Ks[jf * 16 + fl][fh * 8]);
    bf16x8 bk1 = *(const bf16x8*)(&Ks[jf * 16 + fl][32 + fh * 8]);
    f32x4 z = {};
    z = __builtin_amdgcn_mfma_f32_16x16x32_bf16(aq0, bk0, z, 0, 0, 0);
    z = __builtin_amdgcn_mfma_f32_16x16x32_bf16(aq1, bk1, z, 0, 0, 0);
    pc[jf] = z;

    bf16x8 bs0 = *(const bf16x8*)(&Sb[jf * 16 + fl][fh * 8]);
    bf16x8 bs1 = *(const bf16x8*)(&Sb[jf * 16 + fl][32 + fh * 8]);
    f32x4 zz = {};
    zz = __builtin_amdgcn_mfma_f32_16x16x32_bf16(aq0, bs0, zz, 0, 0, 0);
    zz = __builtin_amdgcn_mfma_f32_16x16x32_bf16(aq1, bs1, zz, 0, 0, 0);
    acc[jf] = zz;
  }

#pragma unroll
  for (int jf = 0; jf < 4; ++jf) {
#pragma unroll
    for (int r = 0; r < 4; ++r) {
      int i = w * 16 + rb + r, j = jf * 16 + fl;
      float val = (j <= i) ? pc[jf][r] * exp2f(lg2g * (float)(i - j)) : 0.f;
      Ps[i][j] = f2bf(val);
    }
  }

  float gi1[4];
#pragma unroll
  for (int r = 0; r < 4; ++r) gi1[r] = exp2f(lg2g * (float)(w * 16 + rb + r + 1));
#pragma unroll
  for (int jf = 0; jf < 4; ++jf)
#pragma unroll
    for (int r = 0; r < 4; ++r) acc[jf][r] *= gi1[r];

  __syncthreads();

  bf16x8 ap0 = *(const bf16x8*)(&Ps[w * 16 + fl][fh * 8]);
  bf16x8 ap1 = *(const bf16x8*)(&Ps[w * 16 + fl][32 + fh * 8]);
#pragma unroll
  for (int jf = 0; jf < 4; ++jf) {
    bf16x8 bv0 = *(const bf16x8*)(&Vt[jf * 16 + fl][fh * 8]);
    bf16x8 bv1 = *(const bf16x8*)(&Vt[jf * 16 + fl][32 + fh * 8]);
    acc[jf] = __builtin_amdgcn_mfma_f32_16x16x32_bf16(ap0, bv0, acc[jf], 0, 0, 0);
    acc[jf] = __builtin_amdgcn_mfma_f32_16x16x32_bf16(ap1, bv1, acc[jf], 0, 0, 0);
  }

  size_t yrow = ((size_t)(b * L_ + c * CSZ_)) * D_ + h * HD_;
#pragma unroll
  for (int jf = 0; jf < 4; ++jf) {
#pragma unroll
    for (int r = 0; r < 4; ++r) {
      int i = w * 16 + rb + r;
      y[yrow + (size_t)i * D_ + jf * 16 + fl] = f2bf(acc[jf][r]);
    }
  }
}

// ---------------- launch ----------------
extern "C" void kernel_launch(void* const* d_in, const int* in_sizes, int n_in,
                              void* d_out, int out_size, void* d_ws, size_t ws_size,
                              hipStream_t stream)
{
  const float* x        = (const float*)d_in[0];
  const float* Wqkv_w   = (const float*)d_in[1];
  const float* Wqkv_b   = (const float*)d_in[2];
  const float* out_w    = (const float*)d_in[3];
  const float* out_b    = (const float*)d_in[4];
  const float* gamma_raw= (const float*)d_in[5];
  float* out = (float*)d_out;

  // workspace carve-up (~210 MB)
  char* ws = (char*)d_ws;
  unsigned short* x_bf    = (unsigned short*)ws; ws += (size_t)16777216 * 2;
  unsigned short* wqkv_bf = (unsigned short*)ws; ws += (size_t)3145728 * 2;
  unsigned short* wout_bf = (unsigned short*)ws; ws += (size_t)1048576 * 2;
  unsigned short* qb      = (unsigned short*)ws; ws += (size_t)16777216 * 2;
  unsigned short* kb      = (unsigned short*)ws; ws += (size_t)16777216 * 2;
  unsigned short* vb      = (unsigned short*)ws; ws += (size_t)16777216 * 2;
  unsigned short* Sbuf    = (unsigned short*)ws; ws += (size_t)16777216 * 2;
  unsigned short* yb      = (unsigned short*)ws; ws += (size_t)16777216 * 2;

  cast_kernel<<<16384, 256, 0, stream>>>(x, x_bf, 16777216);
  cast_kernel<<<3072, 256, 0, stream>>>(Wqkv_w, wqkv_bf, 3145728);
  cast_kernel<<<1024, 256, 0, stream>>>(out_w, wout_bf, 1048576);

  // qkv = x @ Wqkv^T + b  -> q/k/v (B,H,L,HD), k pre-scaled.  grid 768 (%8==0)
  gemm_qkv8<<<64 * 12, 512, 0, stream>>>(x_bf, wqkv_bf, Wqkv_b,
                                         qb, kb, vb, M1_, ND3_, D_);

  ret_phase1<<<4096, 256, 0, stream>>>(kb, vb, gamma_raw, Sbuf);
  ret_phase2<<<512, 256, 0, stream>>>(Sbuf, gamma_raw);
  ret_phase3<<<4096, 256, 0, stream>>>(qb, kb, vb, Sbuf, gamma_raw, yb);

  // out = y @ out_w^T + out_b  (fp32 out).  round-5 pinned 128x128, grid 1024, 3 blk/CU
  gemm_out<<<128 * 8, 256, 0, stream>>>(yb, wout_bf, out_b, out, M1_, D_, D_);
}

// Round 12
// 233.333 us; speedup vs baseline: 1.4194x; 1.0399x over previous
//
#include <hip/hip_runtime.h>
#include <cstdint>
#include <cstddef>

// Problem constants
#define B_    4
#define L_    4096
#define D_    1024
#define H_    16
#define HD_   64
#define ND3_  3072          // 3*D
#define M1_   16384         // B*L
#define NCH_  64            // number of chunks
#define CSZ_  64            // chunk size
#define SCALE_ 0.125f       // 1/sqrt(HD)

typedef __attribute__((ext_vector_type(8))) __bf16 bf16x8;
typedef __attribute__((ext_vector_type(4))) float f32x4;
typedef __attribute__((ext_vector_type(4))) unsigned int uint4v;

__device__ __forceinline__ float u2f(unsigned int u) { return __builtin_bit_cast(float, u); }
__device__ __forceinline__ unsigned int f2u(float f) { return __builtin_bit_cast(unsigned int, f); }
__device__ __forceinline__ float bf2f(unsigned short s) { return u2f(((unsigned int)s) << 16); }
__device__ __forceinline__ unsigned short f2bf(float f) {
  unsigned int u = f2u(f);
  u = u + 0x7fffu + ((u >> 16) & 1u);   // RNE
  return (unsigned short)(u >> 16);
}

// async global->LDS, 16B per lane. LDS dest wave-uniform base (+lane*16 implicit).
__device__ __forceinline__ void glds16(const unsigned short* g, unsigned short* l) {
  __builtin_amdgcn_global_load_lds(
      (const __attribute__((address_space(1))) void*)(uintptr_t)g,
      (__attribute__((address_space(3))) void*)(uintptr_t)l, 16, 0, 0);
}

// ---------------- fp32 -> bf16 cast, 3 arrays in one launch ----------------
__global__ __launch_bounds__(256) void cast3_kernel(
    const float* __restrict__ x, unsigned short* __restrict__ xo,
    const float* __restrict__ w1, unsigned short* __restrict__ w1o,
    const float* __restrict__ w2, unsigned short* __restrict__ w2o)
{
  const float* in; unsigned short* out; int i;
  int blk = blockIdx.x;
  if (blk < 16384)      { in = x;  out = xo;  i = (blk * 256 + threadIdx.x) * 4; }
  else if (blk < 19456) { in = w1; out = w1o; i = ((blk - 16384) * 256 + threadIdx.x) * 4; }
  else                  { in = w2; out = w2o; i = ((blk - 19456) * 256 + threadIdx.x) * 4; }
  float4 f = *(const float4*)(in + i);
  out[i + 0] = f2bf(f.x);
  out[i + 1] = f2bf(f.y);
  out[i + 2] = f2bf(f.z);
  out[i + 3] = f2bf(f.w);
}

// ---------------- 256x256 BK=64 8-phase GEMM (race-verified r11 skeleton) --------------
// 8 waves (2Mx4N). Per-wave C 128x64 as 4 quadrants interleaved across halves. LDS =
// 2 dbuf x {A,B} x 2 half x 128x64 bf16 = 128 KB. Staging p1:A1(t+1) p2:B1(t+1)
// p3:B0(t+2) p4:A0(t+2); one counted vmcnt(4)/K-tile at p4; prologue vmcnt(4)+s_barrier.
// EPI 0: scatter q/k/v (B,H,L,HD) bf16, k*SCALE.  EPI 1: fp32 C = acc + bias.
template<int EPI>
__global__ __launch_bounds__(512, 2)
void gemm8(const unsigned short* __restrict__ A, const unsigned short* __restrict__ Bm,
           const float* __restrict__ bias,
           unsigned short* __restrict__ qo, unsigned short* __restrict__ ko,
           unsigned short* __restrict__ vo, float* __restrict__ Co,
           int M, int N, int K)
{
  __shared__ __align__(16) unsigned short Ab[2 * 2 * 8192];  // [dbuf][half][128][64]
  __shared__ __align__(16) unsigned short Bb[2 * 2 * 8192];

  const int nwg = gridDim.x;
  const int wg = (blockIdx.x & 7) * (nwg >> 3) + (blockIdx.x >> 3);
  const int nbn = N >> 8;
  const int bm = wg / nbn, bn = wg - bm * nbn;
  const int m0 = bm << 8, n0 = bn << 8;
  const int tid = threadIdx.x;
  const int lane = tid & 63, wid = tid >> 6;
  const int wr = wid >> 2, wc = wid & 3;        // 2 x 4 wave grid
  const int fl = lane & 15, fh = lane >> 4;
  const int swz = fl & 7;

  const int nt = K >> 6;                        // K-tiles of BK=64

  const int srow = lane >> 3;
  const int slc = (lane & 7) ^ srow;

  f32x4 acc[2][2][4][2] = {};   // [mh][nh][m][n]

  auto stage = [&](const unsigned short* Mat, int rbase, int h, int kt,
                   unsigned short* buf) {
    const int d = kt & 1;
#pragma unroll
    for (int s = 0; s < 2; ++s) {
      const int rl = (wid * 2 + s) * 8 + srow;
      glds16(Mat + (size_t)(rbase + h * 128 + rl) * K + kt * 64 + slc * 8,
             buf + (d * 2 + h) * 8192 + (wid * 2 + s) * 512);
    }
  };

  // prologue: tile0 {A0,B0,A1,B1}, tile1 {B0,A0}; vmcnt(4) + BARRIER (r11 fix)
  stage(A, m0, 0, 0, Ab); stage(Bm, n0, 0, 0, Bb);
  stage(A, m0, 1, 0, Ab); stage(Bm, n0, 1, 0, Bb);
  stage(Bm, n0, 0, 1, Bb); stage(A, m0, 0, 1, Ab);
  asm volatile("s_waitcnt vmcnt(4)" ::: "memory");
  __builtin_amdgcn_s_barrier();
  __builtin_amdgcn_sched_barrier(0);

  for (int t = 0; t < nt; ++t) {
    const int d = t & 1;
    const unsigned short* Abuf = Ab + d * 16384;
    const unsigned short* Bbuf = Bb + d * 16384;
    bf16x8 af0[4][2], af1[4][2], bf0[2][2], bf1[2][2];

    // ---- phase 1: quadrant (0,0); stage A1(t+1) ----
#pragma unroll
    for (int m = 0; m < 4; ++m)
#pragma unroll
      for (int ks = 0; ks < 2; ++ks)
        af0[m][ks] = *(const bf16x8*)(Abuf + (wr * 64 + m * 16 + fl) * 64 + ((ks * 4 + fh) ^ swz) * 8);
#pragma unroll
    for (int n = 0; n < 2; ++n)
#pragma unroll
      for (int ks = 0; ks < 2; ++ks)
        bf0[n][ks] = *(const bf16x8*)(Bbuf + (wc * 32 + n * 16 + fl) * 64 + ((ks * 4 + fh) ^ swz) * 8);
    if (t + 1 < nt) stage(A, m0, 1, t + 1, Ab);
    __builtin_amdgcn_s_barrier();
    asm volatile("s_waitcnt lgkmcnt(0)" ::: "memory");
    __builtin_amdgcn_sched_barrier(0);
    __builtin_amdgcn_s_setprio(1);
#pragma unroll
    for (int m = 0; m < 4; ++m)
#pragma unroll
      for (int n = 0; n < 2; ++n)
#pragma unroll
        for (int ks = 0; ks < 2; ++ks)
          acc[0][0][m][n] = __builtin_amdgcn_mfma_f32_16x16x32_bf16(af0[m][ks], bf0[n][ks], acc[0][0][m][n], 0, 0, 0);
    __builtin_amdgcn_s_setprio(0);
    __builtin_amdgcn_s_barrier();

    // ---- phase 2: quadrant (1,0); stage B1(t+1) ----
#pragma unroll
    for (int m = 0; m < 4; ++m)
#pragma unroll
      for (int ks = 0; ks < 2; ++ks)
        af1[m][ks] = *(const bf16x8*)(Abuf + 8192 + (wr * 64 + m * 16 + fl) * 64 + ((ks * 4 + fh) ^ swz) * 8);
    if (t + 1 < nt) stage(Bm, n0, 1, t + 1, Bb);
    __builtin_amdgcn_s_barrier();
    asm volatile("s_waitcnt lgkmcnt(0)" ::: "memory");
    __builtin_amdgcn_sched_barrier(0);
    __builtin_amdgcn_s_setprio(1);
#pragma unroll
    for (int m = 0; m < 4; ++m)
#pragma unroll
      for (int n = 0; n < 2; ++n)
#pragma unroll
        for (int ks = 0; ks < 2; ++ks)
          acc[1][0][m][n] = __builtin_amdgcn_mfma_f32_16x16x32_bf16(af1[m][ks], bf0[n][ks], acc[1][0][m][n], 0, 0, 0);
    __builtin_amdgcn_s_setprio(0);
    __builtin_amdgcn_s_barrier();

    // ---- phase 3: quadrant (0,1); stage B0(t+2) ----
#pragma unroll
    for (int n = 0; n < 2; ++n)
#pragma unroll
      for (int ks = 0; ks < 2; ++ks)
        bf1[n][ks] = *(const bf16x8*)(Bbuf + 8192 + (wc * 32 + n * 16 + fl) * 64 + ((ks * 4 + fh) ^ swz) * 8);
    if (t + 2 < nt) stage(Bm, n0, 0, t + 2, Bb);
    __builtin_amdgcn_s_barrier();
    asm volatile("s_waitcnt lgkmcnt(0)" ::: "memory");
    __builtin_amdgcn_sched_barrier(0);
    __builtin_amdgcn_s_setprio(1);
#pragma unroll
    for (int m = 0; m < 4; ++m)
#pragma unroll
      for (int n = 0; n < 2; ++n)
#pragma unroll
        for (int ks = 0; ks < 2; ++ks)
          acc[0][1][m][n] = __builtin_amdgcn_mfma_f32_16x16x32_bf16(af0[m][ks], bf1[n][ks], acc[0][1][m][n], 0, 0, 0);
    __builtin_amdgcn_s_setprio(0);
    __builtin_amdgcn_s_barrier();

    // ---- phase 4: quadrant (1,1); stage A0(t+2); per-tile counted vmcnt ----
    if (t + 2 < nt) stage(A, m0, 0, t + 2, Ab);
    __builtin_amdgcn_s_setprio(1);
#pragma unroll
    for (int m = 0; m < 4; ++m)
#pragma unroll
      for (int n = 0; n < 2; ++n)
#pragma unroll
        for (int ks = 0; ks < 2; ++ks)
          acc[1][1][m][n] = __builtin_amdgcn_mfma_f32_16x16x32_bf16(af1[m][ks], bf1[n][ks], acc[1][1][m][n], 0, 0, 0);
    __builtin_amdgcn_s_setprio(0);
    if (t < nt - 2) { asm volatile("s_waitcnt vmcnt(4)" ::: "memory"); }
    else            { asm volatile("s_waitcnt vmcnt(0)" ::: "memory"); }
    __builtin_amdgcn_s_barrier();
    __builtin_amdgcn_sched_barrier(0);
  }

  // epilogue: 16x16 C layout [m89]: row_loc = fh*4 + r, col_loc = fl
  const int rb = fh << 2;
#pragma unroll
  for (int mh = 0; mh < 2; ++mh) {
#pragma unroll
    for (int nh = 0; nh < 2; ++nh) {
#pragma unroll
      for (int m = 0; m < 4; ++m) {
#pragma unroll
        for (int n = 0; n < 2; ++n) {
#pragma unroll
          for (int r = 0; r < 4; ++r) {
            int row = m0 + mh * 128 + wr * 64 + m * 16 + rb + r;
            int col = n0 + nh * 128 + wc * 32 + n * 16 + fl;
            float val = acc[mh][nh][m][n][r] + bias[col];
            if constexpr (EPI == 0) {
              int which = col >> 10;          // n / 1024
              int hh = (col >> 6) & 15;       // (n/64)%16
              int hd = col & 63;
              int bb = row >> 12;             // row / L
              int tt2 = row & 4095;
              size_t idx = (((size_t)(bb * H_ + hh)) * L_ + tt2) * HD_ + hd;
              if (which == 0)      qo[idx] = f2bf(val);
              else if (which == 1) ko[idx] = f2bf(val * SCALE_);
              else                 vo[idx] = f2bf(val);
            } else {
              Co[(size_t)row * N + col] = val;
            }
          }
        }
      }
    }
  }
}

// ---------------- retention phase 1 (MFMA): A_c[a][b] = sum_j g^{63-j} v_j[a] k_j[b] ----------------
__global__ __launch_bounds__(256) void ret_phase1(
    const unsigned short* __restrict__ kb, const unsigned short* __restrict__ vb,
    const float* __restrict__ gamma_raw, unsigned short* __restrict__ Sbuf)
{
  int bhc = blockIdx.x;
  int c = bhc & 63, bh = bhc >> 6, h = bh & 15;
  float g = 1.f / (1.f + expf(-gamma_raw[h]));
  float lg2g = log2f(g);

  __shared__ __align__(16) unsigned short Kt[64][72];
  __shared__ __align__(16) unsigned short Vwt[64][72];

  int tid = threadIdx.x;
  size_t base = ((size_t)bh * L_ + (size_t)c * CSZ_) * HD_;
#pragma unroll
  for (int qq = 0; qq < 16; ++qq) {
    int e = tid + qq * 256;
    int j = e >> 6, col = e & 63;
    float wj = exp2f(lg2g * (float)(63 - j));
    Kt[col][j] = kb[base + e];
    Vwt[col][j] = f2bf(bf2f(vb[base + e]) * wj);
  }
  __syncthreads();

  int lane = tid & 63, w = tid >> 6;
  int fl = lane & 15, fh = lane >> 4;

  bf16x8 av0 = *(const bf16x8*)(&Vwt[w * 16 + fl][fh * 8]);
  bf16x8 av1 = *(const bf16x8*)(&Vwt[w * 16 + fl][32 + fh * 8]);

  int rb = fh << 2;
  unsigned short* out = Sbuf + (size_t)bhc * 4096;
#pragma unroll
  for (int jf = 0; jf < 4; ++jf) {
    bf16x8 bk0 = *(const bf16x8*)(&Kt[jf * 16 + fl][fh * 8]);
    bf16x8 bk1 = *(const bf16x8*)(&Kt[jf * 16 + fl][32 + fh * 8]);
    f32x4 z = {};
    z = __builtin_amdgcn_mfma_f32_16x16x32_bf16(av0, bk0, z, 0, 0, 0);
    z = __builtin_amdgcn_mfma_f32_16x16x32_bf16(av1, bk1, z, 0, 0, 0);
#pragma unroll
    for (int r = 0; r < 4; ++r) {
      int a = w * 16 + rb + r, bcol = jf * 16 + fl;
      out[a * 64 + bcol] = f2bf(z[r]);
    }
  }
}

// ---------------- retention phase 2: in-place decay scan over chunks (bf16 storage) ----------------
__global__ __launch_bounds__(256) void ret_phase2(unsigned short* __restrict__ Sbuf,
                                                  const float* __restrict__ gamma_raw)
{
  int bh = blockIdx.x >> 3, grp = blockIdx.x & 7;
  int h = bh & 15;
  float g = 1.f / (1.f + expf(-gamma_raw[h]));
  float gC = powf(g, 64.f);
  int e = (grp * 256 + threadIdx.x) * 2;
  unsigned short* base = Sbuf + (size_t)bh * (NCH_ * 4096) + e;
  float s0 = 0.f, s1 = 0.f;
  for (int c = 0; c < NCH_; ++c) {
    unsigned int u = *(unsigned int*)(base + (size_t)c * 4096);
    float a0 = bf2f((unsigned short)(u & 0xffffu));
    float a1 = bf2f((unsigned short)(u >> 16));
    *(unsigned int*)(base + (size_t)c * 4096) =
        (unsigned int)f2bf(s0) | ((unsigned int)f2bf(s1) << 16);
    s0 = gC * s0 + a0;
    s1 = gC * s1 + a1;
  }
}

// ---------------- retention phase 3 (MFMA): Y = (D ∘ QK^T) V + g^{i+1} (Q S^T) ----------------
__global__ __launch_bounds__(256) void ret_phase3(
    const unsigned short* __restrict__ qb, const unsigned short* __restrict__ kb,
    const unsigned short* __restrict__ vb, const unsigned short* __restrict__ Sbuf,
    const float* __restrict__ gamma_raw, unsigned short* __restrict__ y)
{
  int bhc = blockIdx.x;
  int c = bhc & 63, bh = bhc >> 6, h = bh & 15, b = bh >> 4;
  float g = 1.f / (1.f + expf(-gamma_raw[h]));
  float lg2g = log2f(g);

  __shared__ __align__(16) unsigned short Qs[64][72];
  __shared__ __align__(16) unsigned short Ks[64][72];
  __shared__ __align__(16) unsigned short Vt[64][72];
  __shared__ __align__(16) unsigned short Sb[64][72];
  __shared__ __align__(16) unsigned short Ps[64][72];

  int tid = threadIdx.x;
  size_t base = ((size_t)bh * L_ + (size_t)c * CSZ_) * HD_;
  const unsigned short* Sp = Sbuf + (size_t)bhc * 4096;
#pragma unroll
  for (int qq = 0; qq < 16; ++qq) {
    int e = tid + qq * 256;
    int r = e >> 6, col = e & 63;
    Qs[r][col] = qb[base + e];
    Ks[r][col] = kb[base + e];
    Vt[col][r] = vb[base + e];
    Sb[r][col] = Sp[e];
  }
  __syncthreads();

  int lane = tid & 63, w = tid >> 6;
  int fl = lane & 15, fh = lane >> 4;
  int rb = fh << 2;

  bf16x8 aq0 = *(const bf16x8*)(&Qs[w * 16 + fl][fh * 8]);
  bf16x8 aq1 = *(const bf16x8*)(&Qs[w * 16 + fl][32 + fh * 8]);

  f32x4 pc[4], acc[4];
#pragma unroll
  for (int jf = 0; jf < 4; ++jf) {
    bf16x8 bk0 = *(const bf16x8*)(&Ks[jf * 16 + fl][fh * 8]);
    bf16x8 bk1 = *(const bf16x8*)(&Ks[jf * 16 + fl][32 + fh * 8]);
    f32x4 z = {};
    z = __builtin_amdgcn_mfma_f32_16x16x32_bf16(aq0, bk0, z, 0, 0, 0);
    z = __builtin_amdgcn_mfma_f32_16x16x32_bf16(aq1, bk1, z, 0, 0, 0);
    pc[jf] = z;

    bf16x8 bs0 = *(const bf16x8*)(&Sb[jf * 16 + fl][fh * 8]);
    bf16x8 bs1 = *(const bf16x8*)(&Sb[jf * 16 + fl][32 + fh * 8]);
    f32x4 zz = {};
    zz = __builtin_amdgcn_mfma_f32_16x16x32_bf16(aq0, bs0, zz, 0, 0, 0);
    zz = __builtin_amdgcn_mfma_f32_16x16x32_bf16(aq1, bs1, zz, 0, 0, 0);
    acc[jf] = zz;
  }

#pragma unroll
  for (int jf = 0; jf < 4; ++jf) {
#pragma unroll
    for (int r = 0; r < 4; ++r) {
      int i = w * 16 + rb + r, j = jf * 16 + fl;
      float val = (j <= i) ? pc[jf][r] * exp2f(lg2g * (float)(i - j)) : 0.f;
      Ps[i][j] = f2bf(val);
    }
  }

  float gi1[4];
#pragma unroll
  for (int r = 0; r < 4; ++r) gi1[r] = exp2f(lg2g * (float)(w * 16 + rb + r + 1));
#pragma unroll
  for (int jf = 0; jf < 4; ++jf)
#pragma unroll
    for (int r = 0; r < 4; ++r) acc[jf][r] *= gi1[r];

  __syncthreads();

  bf16x8 ap0 = *(const bf16x8*)(&Ps[w * 16 + fl][fh * 8]);
  bf16x8 ap1 = *(const bf16x8*)(&Ps[w * 16 + fl][32 + fh * 8]);
#pragma unroll
  for (int jf = 0; jf < 4; ++jf) {
    bf16x8 bv0 = *(const bf16x8*)(&Vt[jf * 16 + fl][fh * 8]);
    bf16x8 bv1 = *(const bf16x8*)(&Vt[jf * 16 + fl][32 + fh * 8]);
    acc[jf] = __builtin_amdgcn_mfma_f32_16x16x32_bf16(ap0, bv0, acc[jf], 0, 0, 0);
    acc[jf] = __builtin_amdgcn_mfma_f32_16x16x32_bf16(ap1, bv1, acc[jf], 0, 0, 0);
  }

  size_t yrow = ((size_t)(b * L_ + c * CSZ_)) * D_ + h * HD_;
#pragma unroll
  for (int jf = 0; jf < 4; ++jf) {
#pragma unroll
    for (int r = 0; r < 4; ++r) {
      int i = w * 16 + rb + r;
      y[yrow + (size_t)i * D_ + jf * 16 + fl] = f2bf(acc[jf][r]);
    }
  }
}

// ---------------- launch ----------------
extern "C" void kernel_launch(void* const* d_in, const int* in_sizes, int n_in,
                              void* d_out, int out_size, void* d_ws, size_t ws_size,
                              hipStream_t stream)
{
  const float* x        = (const float*)d_in[0];
  const float* Wqkv_w   = (const float*)d_in[1];
  const float* Wqkv_b   = (const float*)d_in[2];
  const float* out_w    = (const float*)d_in[3];
  const float* out_b    = (const float*)d_in[4];
  const float* gamma_raw= (const float*)d_in[5];
  float* out = (float*)d_out;

  // workspace carve-up (~210 MB)
  char* ws = (char*)d_ws;
  unsigned short* x_bf    = (unsigned short*)ws; ws += (size_t)16777216 * 2;
  unsigned short* wqkv_bf = (unsigned short*)ws; ws += (size_t)3145728 * 2;
  unsigned short* wout_bf = (unsigned short*)ws; ws += (size_t)1048576 * 2;
  unsigned short* qb      = (unsigned short*)ws; ws += (size_t)16777216 * 2;
  unsigned short* kb      = (unsigned short*)ws; ws += (size_t)16777216 * 2;
  unsigned short* vb      = (unsigned short*)ws; ws += (size_t)16777216 * 2;
  unsigned short* Sbuf    = (unsigned short*)ws; ws += (size_t)16777216 * 2;
  unsigned short* yb      = (unsigned short*)ws; ws += (size_t)16777216 * 2;

  cast3_kernel<<<20480, 256, 0, stream>>>(x, x_bf, Wqkv_w, wqkv_bf, out_w, wout_bf);

  // qkv = x @ Wqkv^T + b  -> q/k/v (B,H,L,HD), k pre-scaled.  grid 768 (%8==0)
  gemm8<0><<<64 * 12, 512, 0, stream>>>(x_bf, wqkv_bf, Wqkv_b,
                                        qb, kb, vb, nullptr, M1_, ND3_, D_);

  ret_phase1<<<4096, 256, 0, stream>>>(kb, vb, gamma_raw, Sbuf);
  ret_phase2<<<512, 256, 0, stream>>>(Sbuf, gamma_raw);
  ret_phase3<<<4096, 256, 0, stream>>>(qb, kb, vb, Sbuf, gamma_raw, yb);

  // out = y @ out_w^T + out_b (fp32).  8-phase 256x256, grid 256 (%8==0), 1 blk/CU
  gemm8<1><<<64 * 4, 512, 0, stream>>>(yb, wout_bf, out_b,
                                       nullptr, nullptr, nullptr, out, M1_, D_, D_);
}